// Round 6
// baseline (209.732 us; speedup 1.0000x reference)
//
#include <hip/hip_runtime.h>
#include <stdint.h>

typedef unsigned short u16;
typedef unsigned int u32;
typedef unsigned long long u64;
typedef __bf16 bf16x8 __attribute__((ext_vector_type(8)));
typedef float floatx4 __attribute__((ext_vector_type(4)));

#define DEVI static __device__ __forceinline__

DEVI u16 f2bf(float f) {
  uint32_t u = __builtin_bit_cast(uint32_t, f);
  u += 0x7FFFu + ((u >> 16) & 1u);
  return (u16)(u >> 16);
}
DEVI float bf2f(u16 b) { return __builtin_bit_cast(float, (uint32_t)b << 16); }

// order-preserving float<->uint encoding
DEVI u32 encf(float f) {
  u32 u = __builtin_bit_cast(u32, f);
  return (u >> 31) ? ~u : (u | 0x80000000u);
}

// 64-lane wave reductions: 6 shuffles, no barriers
DEVI float wred_sum(float v) {
  #pragma unroll
  for (int o = 32; o > 0; o >>= 1) v += __shfl_xor(v, o);
  return v;
}
DEVI float wred_max(float v) {
  #pragma unroll
  for (int o = 32; o > 0; o >>= 1) v = fmaxf(v, __shfl_xor(v, o));
  return v;
}

// async global->LDS 16B (lds dest = wave-uniform base + lane*16)
DEVI void cp16(const u16* g, u16* l) {
#if __has_builtin(__builtin_amdgcn_global_load_lds)
  __builtin_amdgcn_global_load_lds(
      (const __attribute__((address_space(1))) uint32_t*)g,
      (__attribute__((address_space(3))) uint32_t*)l, 16, 0, 0);
#else
  *(uint4*)l = *(const uint4*)g;
#endif
}

// ---- workspace layout (bytes) ----
static constexpr size_t OFF_CORRP = 0;                                   // f32 [cb4][m][n][65][65]
static constexpr size_t OFF_SATT  = OFF_CORRP + (size_t)4*270400*4;      // bf16 [m][cb][y][x][c8]
static constexpr size_t OFF_GRDP  = OFF_SATT + (size_t)8*4*96*96*8*2;    // bf16 [cb][i*32+j][col16][c8]
static constexpr size_t OFF_S2    = OFF_GRDP + (size_t)4*1024*16*8*2;    // f32 [8][96][96]
static constexpr size_t OFF_PART  = OFF_S2   + (size_t)73728*4;          // f32 [8][65][65]
static constexpr size_t OFF_NRMP  = OFF_PART + (size_t)33800*4;          // f32 sat nrm partials [8][96]
static constexpr size_t OFF_GNRM  = OFF_NRMP + 768*4;                    // f32 grd nrm2 [8]
static constexpr size_t OFF_MASK  = OFF_GNRM + 32;                       // f32 [8][1024]
static constexpr size_t OFF_PMAX  = OFF_MASK + (size_t)8192*4;           // u32 enc chunk max [320]
static constexpr size_t OFF_CNT   = OFF_PMAX + 320*4;                    // 512B control block (u32 idx):
//   [0..63] grpcnt  [64..71] candcnt  [72] ticket  [88..95] rdone[8]
//   [96..111] u64 bestu[8] (byte off 384)  [112..119] cscN[8]  [120..127] pscN[8]
static constexpr size_t OFF_CAND  = OFF_CNT  + 512;                      // u64 cand[8][128]

// ---- K1: blocks 0..767: one sat row -> bf16 channels-last + s2 + norm partial.
//          blocks 768..775: grd pack. block 776: zero/seed control block.
__global__ __launch_bounds__(256) void k_prep(
    const float* __restrict__ grd, const float* __restrict__ sat,
    u16* __restrict__ sTh, u16* __restrict__ gP,
    float* __restrict__ s2, float* __restrict__ nrmp,
    float* __restrict__ gnrm, float* __restrict__ gmask,
    u32* __restrict__ cnts) {
  __shared__ float L[32*100];
  __shared__ float red[4];
  const int t = threadIdx.x;
  if (blockIdx.x < 768) {
    const int m = blockIdx.x / 96, y = blockIdx.x - (blockIdx.x / 96) * 96;
    #pragma unroll
    for (int k = 0; k < 3; ++k) {
      const int idx = k*256 + t;
      const int c = idx / 24, xq = idx - c*24;
      const float4 v = *(const float4*)(sat + (((size_t)m*32 + c)*128 + (16+y))*128 + 16 + xq*4);
      *(float4*)(&L[c*100 + xq*4]) = v;
    }
    __syncthreads();
    float ss = 0.f;
    if (t < 96) {
      #pragma unroll
      for (int c = 0; c < 32; ++c) { const float v = L[c*100 + t]; ss += v*v; }
      s2[(size_t)m*9216 + y*96 + t] = ss;
    }
    const float wsum = wred_sum(ss);
    if ((t & 63) == 0) red[t >> 6] = wsum;
    __syncthreads();
    if (t == 0) nrmp[m*96 + y] = red[0] + red[1] + red[2] + red[3];
    for (int idx = t; idx < 384; idx += 256) {
      const int cb = idx / 96, x = idx - cb*96;
      union { u16 us[8]; uint4 v4; } P;
      #pragma unroll
      for (int e = 0; e < 8; ++e) P.us[e] = f2bf(L[(cb*8+e)*100 + x]);
      *(uint4*)(&sTh[(((size_t)m*4+cb)*9216 + (size_t)y*96 + x)*8]) = P.v4;
    }
  } else if (blockIdx.x == 776) {
    // zero grpcnt/candcnt/rdone; ticket=1024 (static tiles 0..1023); seed
    // bestu[n]=0x00000000FFFFFFFF (=> decoded bix=0 when nothing passes).
    if (t < 112)
      cnts[t] = (t == 72) ? 1024u
              : ((t >= 96 && !(t & 1)) ? 0xFFFFFFFFu : 0u);
  } else {
    const int n = blockIdx.x - 768;
    float nn = 0.f, scs[4];
    #pragma unroll
    for (int it = 0; it < 4; ++it) {
      const int pidx = it*256 + t;
      float vals[32]; float sc = 0.f;
      #pragma unroll
      for (int c = 0; c < 32; ++c) {
        const float v = grd[((size_t)n*32 + c)*1024 + pidx];
        vals[c] = v; sc += v; nn += v*v;
      }
      scs[it] = sc;
      #pragma unroll
      for (int cb = 0; cb < 4; ++cb) {
        union { u16 us[8]; uint4 v4; } ph, pl;
        #pragma unroll
        for (int e = 0; e < 8; ++e) {
          const float v = vals[cb*8+e];
          const u16 h = f2bf(v); ph.us[e] = h; pl.us[e] = f2bf(v - bf2f(h));
        }
        const size_t o = ((size_t)cb*1024 + pidx)*128;
        *(uint4*)(&gP[o + (size_t)n*8])     = ph.v4;
        *(uint4*)(&gP[o + (size_t)(n+8)*8]) = pl.v4;
      }
    }
    const float tot = wred_sum(nn);
    if ((t & 63) == 0) red[t >> 6] = tot;
    __syncthreads();
    const float sum = red[0] + red[1] + red[2] + red[3];
    if (t == 0) gnrm[n] = sum;
    const float gn = fmaxf(sqrtf(sum), 1e-12f);
    const float thr = 1e-6f * gn;
    #pragma unroll
    for (int it = 0; it < 4; ++it)
      gmask[n*1024 + it*256 + t] = (fabsf(scs[it]) > thr) ? 1.f : 0.f;
  }
}

// ---- K2: persistent blocks (grid=1024, 4/CU) draining 1128 tile tickets.
//      tiles 0..71: part windows; 72..967: main conv; 968..1127: edge x=64.
//      4 blocks/CU (LDS 4x31744=124KB<160KB, VGPR 84<128): 4 independent
//      MFMA streams per SIMD to hide stage-wait/epilogue/ticket gaps.
__global__ __launch_bounds__(256, 4) void k_conv(
    const u16* __restrict__ satT, const u16* __restrict__ gP,
    const float* __restrict__ s2, float* __restrict__ corr_p,
    float* __restrict__ part, u32* __restrict__ tick)
{
  __shared__ __align__(16) u16 patch[41*48*8];   // 31488 B
  __shared__ u32 s_bi;

  const int tid = threadIdx.x;
  const int wave = tid >> 6, lane = tid & 63;
  const int pr = lane & 15, q = lane >> 4;

  u32 bi = blockIdx.x;           // first tile static (keeps part tiles first)
  for (;;) {
    if (bi < 72) {               // ---- part tile ----
      float* S  = (float*)patch;          // [<=40][96]
      float* HS = S + 40*96;              // [<=39][65]
      const int pm = (int)bi / 9, ysl = ((int)bi - pm*9)*8;
      const int nrows = (65 - ysl) < 8 ? (65 - ysl) : 8;
      const int scnt  = (96 - ysl) < 40 ? (96 - ysl) : 40;
      for (int idx = tid; idx < scnt*96; idx += 256)
        S[idx] = s2[(size_t)pm*9216 + (size_t)ysl*96 + idx];
      __syncthreads();
      const int hrows = nrows + 31;
      for (int idx = tid; idx < hrows*65; idx += 256) {
        const int r = idx / 65, xo = idx - r*65;
        const float* p = &S[r*96 + xo];
        float s = 0.f;
        #pragma unroll
        for (int j = 0; j < 32; ++j) s += p[j];
        HS[idx] = s;
      }
      __syncthreads();
      for (int idx = tid; idx < nrows*65; idx += 256) {
        const int r = idx / 65, xo = idx - r*65;
        float s = 0.f;
        #pragma unroll
        for (int i = 0; i < 32; ++i) s += HS[(r+i)*65 + xo];
        part[(size_t)pm*4225 + (size_t)(ysl+r)*65 + xo] = s;
      }
    } else if (bi >= 968) {      // ---- edge tile: x = 64 column ----
      const int e = (int)bi - 968;
      const int cb = e & 3;
      const int yt = (e >> 2) % 5;
      const int m  = e / 20;
      const int ybase = yt * 13;
      const size_t rowbase = ((size_t)(m*4 + cb) * 96 + ybase) * 96;
      for (int k = tid; k < 44*32; k += 256) {
        const int rho = k >> 5, px = k & 31;
        cp16(&satT[(rowbase + (size_t)rho*96 + 64 + px)*8], &patch[(size_t)k*8]);
      }
      asm volatile("s_waitcnt vmcnt(0)" ::: "memory");
      __syncthreads();
      const int prc = pr < 13 ? pr : 12;   // rows 13-15 duplicate row 12
      floatx4 acc = (floatx4){0.f, 0.f, 0.f, 0.f};
      #pragma unroll
      for (int jbi = 0; jbi < 2; ++jbi) {
        const int jb = wave*2 + jbi;
        const int px_e = jb*4 + q;
        const u16* bp = gP + ((size_t)cb*1024 + (size_t)(jb*4+q))*128 + (size_t)pr*8;
        uint4 Br[8];
        #pragma unroll
        for (int ii = 0; ii < 8; ++ii) Br[ii] = *(const uint4*)(bp + (size_t)ii*4096);
        uint4 Ah[8];
        #pragma unroll
        for (int s = 0; s < 6; ++s)
          Ah[s] = *(const uint4*)(&patch[((size_t)(prc + s)*32 + px_e)*8]);
        #pragma unroll
        for (int i = 0; i < 32; ++i) {
          if (i < 26)
            Ah[(i+6)&7] = *(const uint4*)(&patch[((size_t)(prc + i + 6)*32 + px_e)*8]);
          const bf16x8 bf = __builtin_bit_cast(bf16x8, Br[i&7]);
          if (i < 24)
            Br[(i+8)&7] = *(const uint4*)(bp + (size_t)(i+8)*4096);
          acc = __builtin_amdgcn_mfma_f32_16x16x32_bf16(
              __builtin_bit_cast(bf16x8, Ah[i&7]), bf, acc, 0, 0, 0);
        }
      }
      float v4[4];
      #pragma unroll
      for (int k = 0; k < 4; ++k) v4[k] = acc[k] + __shfl_xor(acc[k], 8);
      __syncthreads();
      float* red = (float*)patch;
      #pragma unroll
      for (int k = 0; k < 4; ++k) red[((size_t)wave*64 + lane)*5 + k] = v4[k];
      __syncthreads();
      if (wave == 0 && pr < 8) {
        #pragma unroll
        for (int k = 0; k < 4; ++k) {
          const int yoff = q*4 + k;
          if (yoff < 13) {
            float s = 0.f;
            #pragma unroll
            for (int w = 0; w < 4; ++w) s += red[((size_t)w*64 + lane)*5 + k];
            corr_p[(size_t)cb*270400 + ((size_t)(m*8+pr)*65 + (ybase+yoff))*65 + 64] = s;
          }
        }
      }
    } else {                     // ---- main conv tile ----
      int bb = (int)bi - 72;
      const int cb = bb & 3; bb >>= 2;
      const int xt = bb & 3; bb >>= 2;
      const int yt = bb % 7;
      const int m  = bb / 7;
      const int x0 = xt*16;

      if (yt < 6) {
        // ======== 10-row tile, rows y0..y0+9, patch 41 rows ========
        const int y0 = yt*10;
        const size_t rowbase = ((size_t)(m*4 + cb) * 96 + y0) * 96;
        for (int k = tid; k < 41*48; k += 256) {
          const int rho = k / 48, px = k - (k/48)*48;
          cp16(&satT[(rowbase + (size_t)rho*96 + x0 + px)*8], &patch[(size_t)k*8]);
        }
        asm volatile("s_waitcnt vmcnt(0)" ::: "memory");
        __syncthreads();

        floatx4 acc[10];
        #pragma unroll
        for (int r = 0; r < 10; ++r) acc[r] = (floatx4){0.f, 0.f, 0.f, 0.f};

        #pragma unroll
        for (int jbi = 0; jbi < 2; ++jbi) {
          const int jb = wave*2 + jbi;
          const int apx = pr + jb*4 + q;                       // <= 46
          const u16* bp = gP + ((size_t)cb*1024 + (size_t)(jb*4+q))*128 + (size_t)pr*8;

          uint4 Br[8];
          #pragma unroll
          for (int ii = 0; ii < 8; ++ii) Br[ii] = *(const uint4*)(bp + (size_t)ii*4096);
          uint4 Ah[12];
          #pragma unroll
          for (int s = 0; s < 12; ++s) Ah[s] = *(const uint4*)(&patch[((size_t)s*48 + apx)*8]);

          #pragma unroll
          for (int i = 0; i < 32; ++i) {
            const bf16x8 bf = __builtin_bit_cast(bf16x8, Br[i&7]);
            if (i < 24)
              Br[(i+8)&7] = *(const uint4*)(bp + (size_t)(i+8)*4096);
            __builtin_amdgcn_s_setprio(1);
            #pragma unroll
            for (int r = 0; r < 10; ++r)
              acc[r] = __builtin_amdgcn_mfma_f32_16x16x32_bf16(
                  __builtin_bit_cast(bf16x8, Ah[(i+r)%12]), bf, acc[r], 0, 0, 0);
            __builtin_amdgcn_s_setprio(0);
            if (i < 29)
              Ah[(i+12)%12] = *(const uint4*)(&patch[((size_t)(i+12)*48 + apx)*8]);
          }
        }

        float* red = (float*)patch;
        #pragma unroll
        for (int half = 0; half < 2; ++half) {
          __syncthreads();
          #pragma unroll
          for (int u = 0; u < 20; ++u)
            red[((size_t)wave*64 + lane)*21 + u] = acc[half*5 + (u>>2)][u&3];
          __syncthreads();
          if (pr < 8) {
            const int fw = wave;
            #pragma unroll
            for (int r = 0; r < 5; ++r) {
              float s = 0.f;
              #pragma unroll
              for (int w = 0; w < 4; ++w)
                s += red[((size_t)w*64 + lane)*21 + r*4 + fw]
                   + red[((size_t)w*64 + (lane^8))*21 + r*4 + fw];
              const int x = x0 + q*4 + fw;    // <= 63
              corr_p[(size_t)cb*270400 + ((size_t)(m*8+pr)*65 + (y0 + half*5 + r))*65 + x] = s;
            }
          }
        }
      } else {
        // ======== 5-row tile, rows 60..64 ========
        const int y0 = 60;
        const size_t rowbase = ((size_t)(m*4 + cb) * 96 + y0) * 96;
        for (int k = tid; k < 36*48; k += 256) {
          const int rho = k / 48, px = k - (k/48)*48;
          cp16(&satT[(rowbase + (size_t)rho*96 + x0 + px)*8], &patch[(size_t)k*8]);
        }
        asm volatile("s_waitcnt vmcnt(0)" ::: "memory");
        __syncthreads();

        floatx4 acc[5];
        #pragma unroll
        for (int r = 0; r < 5; ++r) acc[r] = (floatx4){0.f, 0.f, 0.f, 0.f};

        #pragma unroll
        for (int jbi = 0; jbi < 2; ++jbi) {
          const int jb = wave*2 + jbi;
          const int apx = pr + jb*4 + q;
          const u16* bp = gP + ((size_t)cb*1024 + (size_t)(jb*4+q))*128 + (size_t)pr*8;

          uint4 Br[8];
          #pragma unroll
          for (int ii = 0; ii < 8; ++ii) Br[ii] = *(const uint4*)(bp + (size_t)ii*4096);
          uint4 Ah[8];
          #pragma unroll
          for (int s = 0; s < 6; ++s) Ah[s] = *(const uint4*)(&patch[((size_t)s*48 + apx)*8]);

          #pragma unroll
          for (int i = 0; i < 32; ++i) {
            if (i < 30)
              Ah[(i+6)&7] = *(const uint4*)(&patch[((size_t)(i+6)*48 + apx)*8]);
            const bf16x8 bf = __builtin_bit_cast(bf16x8, Br[i&7]);
            if (i < 24)
              Br[(i+8)&7] = *(const uint4*)(bp + (size_t)(i+8)*4096);
            __builtin_amdgcn_s_setprio(1);
            #pragma unroll
            for (int r = 0; r < 5; ++r)
              acc[r] = __builtin_amdgcn_mfma_f32_16x16x32_bf16(
                  __builtin_bit_cast(bf16x8, Ah[(i+r)&7]), bf, acc[r], 0, 0, 0);
            __builtin_amdgcn_s_setprio(0);
          }
        }

        __syncthreads();
        float* red = (float*)patch;
        #pragma unroll
        for (int u = 0; u < 20; ++u)
          red[((size_t)wave*64 + lane)*21 + u] = acc[u>>2][u&3];
        __syncthreads();
        if (pr < 8) {
          const int fw = wave;
          #pragma unroll
          for (int r = 0; r < 5; ++r) {
            float s = 0.f;
            #pragma unroll
            for (int w = 0; w < 4; ++w)
              s += red[((size_t)w*64 + lane)*21 + r*4 + fw]
                 + red[((size_t)w*64 + (lane^8))*21 + r*4 + fw];
            const int x = x0 + q*4 + fw;
            corr_p[(size_t)cb*270400 + ((size_t)(m*8+pr)*65 + (y0+r))*65 + x] = s;
          }
        }
      }
    }

    // ---- next ticket (patch reuse guarded by the barrier pair) ----
    __syncthreads();
    if (tid == 0) s_bi = atomicAdd(tick, 1u);
    __syncthreads();
    bi = s_bi;
    if (bi >= 1128) return;
  }
}

// ---- K3: streaming normalize/max + candidate collect + gmax gather. ----
__global__ __launch_bounds__(256) void k_post(
    const float* __restrict__ corr_p, const float* __restrict__ part,
    const float* __restrict__ nrmp, const float* __restrict__ gnrm,
    const int* __restrict__ tm,
    u32* __restrict__ pmaxE, u32* __restrict__ grpcnt,
    u32* __restrict__ candcnt, u64* __restrict__ cand,
    float* __restrict__ cscN, float* __restrict__ pscN,
    float* __restrict__ out)
{
  __shared__ float red[8];
  __shared__ int s_last;

  const int bi = blockIdx.x;
  const int m = bi / 40, n = (bi / 5) & 7, yc = bi % 5, g = m*8 + n;
  const int t = threadIdx.x;
  const int wv = t >> 6, ln = t & 63;
  const bool diag = (m == n);

  float v0 = (t < 96) ? nrmp[m*96 + t] : 0.f;
  v0 = wred_sum(v0);
  if (ln == 0) red[wv] = v0;
  __syncthreads();
  const float snrm2 = red[0] + red[1] + red[2] + red[3];
  const float srn = 1.f / fmaxf(sqrtf(snrm2), 1e-12f);
  const float grn = 1.f / fmaxf(sqrtf(gnrm[n]), 1e-12f);
  const float cscale = grn * srn, pscale = srn * srn;
  const int method = tm[0];
  if (diag && t == 0) { cscN[n] = cscale; pscN[n] = pscale; }   // for k_refine

  const float* cp = corr_p + (size_t)g*4225;
  const float* pp = part + (size_t)m*4225;
  const int i0 = yc*845, i1 = i0 + 845;
  float vv[4];
  float bestv = -3.4e38f;
  #pragma unroll
  for (int k = 0; k < 4; ++k) {
    const int idx = i0 + k*256 + t;
    float v = -3.4e38f;
    if (idx < i1) {
      const float c = cp[idx] + cp[idx+270400] + cp[idx+540800] + cp[idx+811200];
      const float pt = pp[idx] * pscale;
      float denom = (method == 0) ? sqrtf(pt) : pt;
      denom = fmaxf(denom, 1e-12f);
      v = c * cscale / denom;
    }
    vv[k] = v;
    bestv = fmaxf(bestv, v);
  }
  __syncthreads();                    // red WAR guard
  const float bw = wred_max(bestv);
  if (ln == 0) red[wv] = bw;
  __syncthreads();
  const float bmax = fmaxf(fmaxf(red[0], red[1]), fmaxf(red[2], red[3]));
  if (t == 0) atomicExch(&pmaxE[bi], encf(bmax));

  if (diag) {
    // collect candidate superset: within 3e-3 of BLOCK max (global filter in k_refine)
    const float lthr = bmax - 3e-3f;
    #pragma unroll
    for (int k = 0; k < 4; ++k) {
      const int idx = i0 + k*256 + t;
      if (idx < i1 && vv[k] >= lthr) {
        const u32 s = atomicAdd(&candcnt[n], 1u);
        if (s < 128)
          atomicExch(&cand[n*128 + s],
                     ((u64)__builtin_bit_cast(u32, vv[k]) << 32) | (u32)idx);
      }
    }
  }
  __syncthreads();
  if (t == 0) s_last = (atomicAdd(&grpcnt[g], 1u) == 4u) ? 1 : 0;
  __syncthreads();
  if (!s_last) return;

  if (t < 5) {
    const u32 e = atomicOr(&pmaxE[g*5 + t], 0u);
    const u32 u = (e >> 31) ? (e & 0x7FFFFFFFu) : ~e;
    red[t] = __builtin_bit_cast(float, u);
  }
  __syncthreads();
  const float gmax = fmaxf(fmaxf(fmaxf(red[0], red[1]), fmaxf(red[2], red[3])), red[4]);
  if (t == 0) out[g] = gmax;
}

// ---- K4: parallel refine + mask. 1024 blocks = 8 n x 128 candidate slots.
//      Each active slot computes one exact f32 dot (coalesced, 256 threads),
//      atomicMax's a (value,~idx) key; last slot per n writes the mask.
//      NO __threadfence (R4 lesson: it is an L2 wb/inv storm, +45us). ----
__global__ __launch_bounds__(256) void k_refine(
    const float* __restrict__ part, const int* __restrict__ tm,
    const float* __restrict__ grd, const float* __restrict__ sat,
    const float* __restrict__ gmask,
    const u32* __restrict__ candcnt, const u64* __restrict__ cand,
    const float* __restrict__ cscN, const float* __restrict__ pscN,
    u32* __restrict__ rdone, u64* __restrict__ bestu,
    float* __restrict__ out)
{
  __shared__ float red[4];
  __shared__ int s_last;

  const int bid = blockIdx.x;
  const int n = bid >> 7, ci = bid & 127;
  const int t = threadIdx.x;
  const int wv = t >> 6, ln = t & 63;

  u32 nc = candcnt[n]; if (nc > 128u) nc = 128u;
  bool act = (ci < (int)nc);
  int idx = 0;
  if (act) {
    const u64 pk = cand[n*128 + ci];
    const float vf = __builtin_bit_cast(float, (u32)(pk >> 32));
    idx = (int)(u32)pk;
    act = (vf >= out[9*n] - 3e-3f);     // global filter (gmax from k_post)
  }
  if (act) {
    const int y = idx / 65, x = idx - y*65;
    const int i0 = t >> 5, j = t & 31;   // lanes sweep j: coalesced 128B runs
    const float* gb = grd + (size_t)n*32768 + i0*32 + j;
    const float* sb = sat + (((size_t)n*32*128) + 16 + y + i0)*128 + 16 + x + j;
    float a = 0.f;
    #pragma unroll 4
    for (int c = 0; c < 32; ++c) {
      #pragma unroll
      for (int ii = 0; ii < 4; ++ii)
        a += gb[(size_t)(c*32 + ii*8)*32] * sb[((size_t)c*128 + ii*8)*128];
    }
    a = wred_sum(a);
    if (ln == 0) red[wv] = a;
    __syncthreads();
    if (t == 0) {
      const float tot = red[0] + red[1] + red[2] + red[3];
      const float pt = part[(size_t)n*4225 + idx] * pscN[n];
      float denom = (tm[0] == 0) ? sqrtf(pt) : pt;
      denom = fmaxf(denom, 1e-12f);
      const float v = tot * cscN[n] / denom;
      const u64 key = ((u64)encf(v) << 32) | (u64)(0xFFFFFFFFu - (u32)idx);
      atomicMax(&bestu[n], key);
    }
  }
  __syncthreads();     // drains vmcnt(0): bestu atomicMax committed before rdone
  if (t == 0) s_last = (atomicAdd(&rdone[n], 1u) == 127u) ? 1 : 0;
  __syncthreads();
  if (!s_last) return;

  const u64 bk = atomicAdd(&bestu[n], 0ULL);
  const int bix = (int)(0xFFFFFFFFu - (u32)bk);
  const int ph = bix / 65, pw = bix - (bix/65)*65;
  for (int p = t; p < 9216; p += 256) {
    const int yy = p / 96, xx = p - yy*96;
    float val = 0.f;
    if (yy >= ph && yy < ph+32 && xx >= pw && xx < pw+32)
      val = gmask[n*1024 + (yy-ph)*32 + (xx-pw)];
    out[64 + (size_t)n*9216 + p] = val;
  }
}

extern "C" void kernel_launch(void* const* d_in, const int* in_sizes, int n_in,
                              void* d_out, int out_size, void* d_ws, size_t ws_size,
                              hipStream_t stream) {
  const float* grd = (const float*)d_in[0];
  const float* sat = (const float*)d_in[1];
  const int*   tm  = (const int*)d_in[2];
  float* out = (float*)d_out;
  char* ws = (char*)d_ws;

  float* corrp = (float*)(ws + OFF_CORRP);
  u16*   sTh   = (u16*)(ws + OFF_SATT);
  u16*   gP    = (u16*)(ws + OFF_GRDP);
  float* s2    = (float*)(ws + OFF_S2);
  float* part  = (float*)(ws + OFF_PART);
  float* nrmp  = (float*)(ws + OFF_NRMP);
  float* gnrm  = (float*)(ws + OFF_GNRM);
  float* gmask = (float*)(ws + OFF_MASK);
  u32*   pmaxE = (u32*)(ws + OFF_PMAX);
  u32*   cnts  = (u32*)(ws + OFF_CNT);
  u32*   candcnt = cnts + 64;
  u32*   tick  = cnts + 72;
  u32*   rdone = cnts + 88;
  u64*   bestu = (u64*)(ws + OFF_CNT + 384);
  float* cscN  = (float*)(cnts + 112);
  float* pscN  = (float*)(cnts + 120);
  u64*   cand  = (u64*)(ws + OFF_CAND);

  k_prep<<<777,  256, 0, stream>>>(grd, sat, sTh, gP, s2, nrmp, gnrm, gmask, cnts);
  k_conv<<<1024, 256, 0, stream>>>(sTh, gP, s2, corrp, part, tick);
  k_post<<<320,  256, 0, stream>>>(corrp, part, nrmp, gnrm, tm,
                                   pmaxE, cnts, candcnt, cand, cscN, pscN, out);
  k_refine<<<1024, 256, 0, stream>>>(part, tm, grd, sat, gmask,
                                     candcnt, cand, cscN, pscN,
                                     rdone, bestu, out);
}

// Round 7
// 148.388 us; speedup vs baseline: 1.4134x; 1.4134x over previous
//
#include <hip/hip_runtime.h>
#include <stdint.h>

typedef unsigned short u16;
typedef unsigned int u32;
typedef unsigned long long u64;
typedef __bf16 bf16x8 __attribute__((ext_vector_type(8)));
typedef float floatx4 __attribute__((ext_vector_type(4)));

#define DEVI static __device__ __forceinline__

DEVI u16 f2bf(float f) {
  uint32_t u = __builtin_bit_cast(uint32_t, f);
  u += 0x7FFFu + ((u >> 16) & 1u);
  return (u16)(u >> 16);
}
DEVI float bf2f(u16 b) { return __builtin_bit_cast(float, (uint32_t)b << 16); }

// order-preserving float<->uint encoding
DEVI u32 encf(float f) {
  u32 u = __builtin_bit_cast(u32, f);
  return (u >> 31) ? ~u : (u | 0x80000000u);
}

// 64-lane wave reductions: 6 shuffles, no barriers
DEVI float wred_sum(float v) {
  #pragma unroll
  for (int o = 32; o > 0; o >>= 1) v += __shfl_xor(v, o);
  return v;
}
DEVI float wred_max(float v) {
  #pragma unroll
  for (int o = 32; o > 0; o >>= 1) v = fmaxf(v, __shfl_xor(v, o));
  return v;
}

// async global->LDS 16B (lds dest = wave-uniform base + lane*16)
DEVI void cp16(const u16* g, u16* l) {
#if __has_builtin(__builtin_amdgcn_global_load_lds)
  __builtin_amdgcn_global_load_lds(
      (const __attribute__((address_space(1))) uint32_t*)g,
      (__attribute__((address_space(3))) uint32_t*)l, 16, 0, 0);
#else
  *(uint4*)l = *(const uint4*)g;
#endif
}

// ---- workspace layout (bytes) ----
static constexpr size_t OFF_CORRP = 0;                                   // f32 [cb4][m][n][65][65]
static constexpr size_t OFF_SATT  = OFF_CORRP + (size_t)4*270400*4;      // bf16 [m][cb][y][x][c8]
static constexpr size_t OFF_GRDP  = OFF_SATT + (size_t)8*4*96*96*8*2;    // bf16 [cb][i*32+j][col16][c8]
static constexpr size_t OFF_S2    = OFF_GRDP + (size_t)4*1024*16*8*2;    // f32 [8][96][96]
static constexpr size_t OFF_PART  = OFF_S2   + (size_t)73728*4;          // f32 [8][65][65]
static constexpr size_t OFF_NRMP  = OFF_PART + (size_t)33800*4;          // f32 sat nrm partials [8][96]
static constexpr size_t OFF_GNRM  = OFF_NRMP + 768*4;                    // f32 grd nrm2 [8]
static constexpr size_t OFF_MASK  = OFF_GNRM + 32;                       // f32 [8][1024]
static constexpr size_t OFF_PMAX  = OFF_MASK + (size_t)8192*4;           // u32 enc chunk max [320]
static constexpr size_t OFF_CNT   = OFF_PMAX + 320*4;                    // 512B control block (u32 idx):
//   [0..63] grpcnt  [64..71] candcnt  [72] ticket  [88..95] rdone[8]
//   [96..111] u64 bestu[8] (byte off 384)  [112..119] cscN[8]  [120..127] pscN[8]
static constexpr size_t OFF_CAND  = OFF_CNT  + 512;                      // u64 cand[8][128]

// ---- K1: blocks 0..767: one sat row -> bf16 channels-last + s2 + norm partial.
//          blocks 768..775: grd pack. block 776: zero/seed control block.
__global__ __launch_bounds__(256) void k_prep(
    const float* __restrict__ grd, const float* __restrict__ sat,
    u16* __restrict__ sTh, u16* __restrict__ gP,
    float* __restrict__ s2, float* __restrict__ nrmp,
    float* __restrict__ gnrm, float* __restrict__ gmask,
    u32* __restrict__ cnts) {
  __shared__ float L[32*100];
  __shared__ float red[4];
  const int t = threadIdx.x;
  if (blockIdx.x < 768) {
    const int m = blockIdx.x / 96, y = blockIdx.x - (blockIdx.x / 96) * 96;
    #pragma unroll
    for (int k = 0; k < 3; ++k) {
      const int idx = k*256 + t;
      const int c = idx / 24, xq = idx - c*24;
      const float4 v = *(const float4*)(sat + (((size_t)m*32 + c)*128 + (16+y))*128 + 16 + xq*4);
      *(float4*)(&L[c*100 + xq*4]) = v;
    }
    __syncthreads();
    float ss = 0.f;
    if (t < 96) {
      #pragma unroll
      for (int c = 0; c < 32; ++c) { const float v = L[c*100 + t]; ss += v*v; }
      s2[(size_t)m*9216 + y*96 + t] = ss;
    }
    const float wsum = wred_sum(ss);
    if ((t & 63) == 0) red[t >> 6] = wsum;
    __syncthreads();
    if (t == 0) nrmp[m*96 + y] = red[0] + red[1] + red[2] + red[3];
    for (int idx = t; idx < 384; idx += 256) {
      const int cb = idx / 96, x = idx - cb*96;
      union { u16 us[8]; uint4 v4; } P;
      #pragma unroll
      for (int e = 0; e < 8; ++e) P.us[e] = f2bf(L[(cb*8+e)*100 + x]);
      *(uint4*)(&sTh[(((size_t)m*4+cb)*9216 + (size_t)y*96 + x)*8]) = P.v4;
    }
  } else if (blockIdx.x == 776) {
    // zero grpcnt/candcnt/rdone; ticket=1024 (static tiles 0..1023); seed
    // bestu[n]=0x00000000FFFFFFFF (=> decoded bix=0 when nothing passes).
    if (t < 112)
      cnts[t] = (t == 72) ? 1024u
              : ((t >= 96 && !(t & 1)) ? 0xFFFFFFFFu : 0u);
  } else {
    const int n = blockIdx.x - 768;
    float nn = 0.f, scs[4];
    #pragma unroll
    for (int it = 0; it < 4; ++it) {
      const int pidx = it*256 + t;
      float vals[32]; float sc = 0.f;
      #pragma unroll
      for (int c = 0; c < 32; ++c) {
        const float v = grd[((size_t)n*32 + c)*1024 + pidx];
        vals[c] = v; sc += v; nn += v*v;
      }
      scs[it] = sc;
      #pragma unroll
      for (int cb = 0; cb < 4; ++cb) {
        union { u16 us[8]; uint4 v4; } ph, pl;
        #pragma unroll
        for (int e = 0; e < 8; ++e) {
          const float v = vals[cb*8+e];
          const u16 h = f2bf(v); ph.us[e] = h; pl.us[e] = f2bf(v - bf2f(h));
        }
        const size_t o = ((size_t)cb*1024 + pidx)*128;
        *(uint4*)(&gP[o + (size_t)n*8])     = ph.v4;
        *(uint4*)(&gP[o + (size_t)(n+8)*8]) = pl.v4;
      }
    }
    const float tot = wred_sum(nn);
    if ((t & 63) == 0) red[t >> 6] = tot;
    __syncthreads();
    const float sum = red[0] + red[1] + red[2] + red[3];
    if (t == 0) gnrm[n] = sum;
    const float gn = fmaxf(sqrtf(sum), 1e-12f);
    const float thr = 1e-6f * gn;
    #pragma unroll
    for (int it = 0; it < 4; ++it)
      gmask[n*1024 + it*256 + t] = (fabsf(scs[it]) > thr) ? 1.f : 0.f;
  }
}

// ---- K2: persistent blocks (grid=1024) draining 1128 tile tickets.
//      tiles 0..71: part windows; 72..967: main conv; 968..1127: edge x=64.
//      launch_bounds STAYS (256,3): R6 proved (256,4) squeezes VGPR 84->64
//      and spills the MFMA loop (WRITE_SIZE 10x). At 84 VGPR / 31744B LDS the
//      HW can pack 4 blocks/CU anyway; grid=1024 just offers the 4th block.
__global__ __launch_bounds__(256, 3) void k_conv(
    const u16* __restrict__ satT, const u16* __restrict__ gP,
    const float* __restrict__ s2, float* __restrict__ corr_p,
    float* __restrict__ part, u32* __restrict__ tick)
{
  __shared__ __align__(16) u16 patch[41*48*8];   // 31488 B
  __shared__ u32 s_bi;

  const int tid = threadIdx.x;
  const int wave = tid >> 6, lane = tid & 63;
  const int pr = lane & 15, q = lane >> 4;

  u32 bi = blockIdx.x;           // first tile static (keeps part tiles first)
  for (;;) {
    if (bi < 72) {               // ---- part tile ----
      float* S  = (float*)patch;          // [<=40][96]
      float* HS = S + 40*96;              // [<=39][65]
      const int pm = (int)bi / 9, ysl = ((int)bi - pm*9)*8;
      const int nrows = (65 - ysl) < 8 ? (65 - ysl) : 8;
      const int scnt  = (96 - ysl) < 40 ? (96 - ysl) : 40;
      for (int idx = tid; idx < scnt*96; idx += 256)
        S[idx] = s2[(size_t)pm*9216 + (size_t)ysl*96 + idx];
      __syncthreads();
      const int hrows = nrows + 31;
      for (int idx = tid; idx < hrows*65; idx += 256) {
        const int r = idx / 65, xo = idx - r*65;
        const float* p = &S[r*96 + xo];
        float s = 0.f;
        #pragma unroll
        for (int j = 0; j < 32; ++j) s += p[j];
        HS[idx] = s;
      }
      __syncthreads();
      for (int idx = tid; idx < nrows*65; idx += 256) {
        const int r = idx / 65, xo = idx - r*65;
        float s = 0.f;
        #pragma unroll
        for (int i = 0; i < 32; ++i) s += HS[(r+i)*65 + xo];
        part[(size_t)pm*4225 + (size_t)(ysl+r)*65 + xo] = s;
      }
    } else if (bi >= 968) {      // ---- edge tile: x = 64 column ----
      const int e = (int)bi - 968;
      const int cb = e & 3;
      const int yt = (e >> 2) % 5;
      const int m  = e / 20;
      const int ybase = yt * 13;
      const size_t rowbase = ((size_t)(m*4 + cb) * 96 + ybase) * 96;
      for (int k = tid; k < 44*32; k += 256) {
        const int rho = k >> 5, px = k & 31;
        cp16(&satT[(rowbase + (size_t)rho*96 + 64 + px)*8], &patch[(size_t)k*8]);
      }
      asm volatile("s_waitcnt vmcnt(0)" ::: "memory");
      __syncthreads();
      const int prc = pr < 13 ? pr : 12;   // rows 13-15 duplicate row 12
      floatx4 acc = (floatx4){0.f, 0.f, 0.f, 0.f};
      #pragma unroll
      for (int jbi = 0; jbi < 2; ++jbi) {
        const int jb = wave*2 + jbi;
        const int px_e = jb*4 + q;
        const u16* bp = gP + ((size_t)cb*1024 + (size_t)(jb*4+q))*128 + (size_t)pr*8;
        uint4 Br[8];
        #pragma unroll
        for (int ii = 0; ii < 8; ++ii) Br[ii] = *(const uint4*)(bp + (size_t)ii*4096);
        uint4 Ah[8];
        #pragma unroll
        for (int s = 0; s < 6; ++s)
          Ah[s] = *(const uint4*)(&patch[((size_t)(prc + s)*32 + px_e)*8]);
        #pragma unroll
        for (int i = 0; i < 32; ++i) {
          if (i < 26)
            Ah[(i+6)&7] = *(const uint4*)(&patch[((size_t)(prc + i + 6)*32 + px_e)*8]);
          const bf16x8 bf = __builtin_bit_cast(bf16x8, Br[i&7]);
          if (i < 24)
            Br[(i+8)&7] = *(const uint4*)(bp + (size_t)(i+8)*4096);
          acc = __builtin_amdgcn_mfma_f32_16x16x32_bf16(
              __builtin_bit_cast(bf16x8, Ah[i&7]), bf, acc, 0, 0, 0);
        }
      }
      float v4[4];
      #pragma unroll
      for (int k = 0; k < 4; ++k) v4[k] = acc[k] + __shfl_xor(acc[k], 8);
      __syncthreads();
      float* red = (float*)patch;
      #pragma unroll
      for (int k = 0; k < 4; ++k) red[((size_t)wave*64 + lane)*5 + k] = v4[k];
      __syncthreads();
      if (wave == 0 && pr < 8) {
        #pragma unroll
        for (int k = 0; k < 4; ++k) {
          const int yoff = q*4 + k;
          if (yoff < 13) {
            float s = 0.f;
            #pragma unroll
            for (int w = 0; w < 4; ++w) s += red[((size_t)w*64 + lane)*5 + k];
            corr_p[(size_t)cb*270400 + ((size_t)(m*8+pr)*65 + (ybase+yoff))*65 + 64] = s;
          }
        }
      }
    } else {                     // ---- main conv tile ----
      int bb = (int)bi - 72;
      const int cb = bb & 3; bb >>= 2;
      const int xt = bb & 3; bb >>= 2;
      const int yt = bb % 7;
      const int m  = bb / 7;
      const int x0 = xt*16;

      if (yt < 6) {
        // ======== 10-row tile, rows y0..y0+9, patch 41 rows ========
        const int y0 = yt*10;
        const size_t rowbase = ((size_t)(m*4 + cb) * 96 + y0) * 96;
        for (int k = tid; k < 41*48; k += 256) {
          const int rho = k / 48, px = k - (k/48)*48;
          cp16(&satT[(rowbase + (size_t)rho*96 + x0 + px)*8], &patch[(size_t)k*8]);
        }
        asm volatile("s_waitcnt vmcnt(0)" ::: "memory");
        __syncthreads();

        floatx4 acc[10];
        #pragma unroll
        for (int r = 0; r < 10; ++r) acc[r] = (floatx4){0.f, 0.f, 0.f, 0.f};

        #pragma unroll
        for (int jbi = 0; jbi < 2; ++jbi) {
          const int jb = wave*2 + jbi;
          const int apx = pr + jb*4 + q;                       // <= 46
          const u16* bp = gP + ((size_t)cb*1024 + (size_t)(jb*4+q))*128 + (size_t)pr*8;

          uint4 Br[8];
          #pragma unroll
          for (int ii = 0; ii < 8; ++ii) Br[ii] = *(const uint4*)(bp + (size_t)ii*4096);
          uint4 Ah[12];
          #pragma unroll
          for (int s = 0; s < 12; ++s) Ah[s] = *(const uint4*)(&patch[((size_t)s*48 + apx)*8]);

          #pragma unroll
          for (int i = 0; i < 32; ++i) {
            const bf16x8 bf = __builtin_bit_cast(bf16x8, Br[i&7]);
            if (i < 24)
              Br[(i+8)&7] = *(const uint4*)(bp + (size_t)(i+8)*4096);
            __builtin_amdgcn_s_setprio(1);
            #pragma unroll
            for (int r = 0; r < 10; ++r)
              acc[r] = __builtin_amdgcn_mfma_f32_16x16x32_bf16(
                  __builtin_bit_cast(bf16x8, Ah[(i+r)%12]), bf, acc[r], 0, 0, 0);
            __builtin_amdgcn_s_setprio(0);
            if (i < 29)
              Ah[(i+12)%12] = *(const uint4*)(&patch[((size_t)(i+12)*48 + apx)*8]);
          }
        }

        float* red = (float*)patch;
        #pragma unroll
        for (int half = 0; half < 2; ++half) {
          __syncthreads();
          #pragma unroll
          for (int u = 0; u < 20; ++u)
            red[((size_t)wave*64 + lane)*21 + u] = acc[half*5 + (u>>2)][u&3];
          __syncthreads();
          if (pr < 8) {
            const int fw = wave;
            #pragma unroll
            for (int r = 0; r < 5; ++r) {
              float s = 0.f;
              #pragma unroll
              for (int w = 0; w < 4; ++w)
                s += red[((size_t)w*64 + lane)*21 + r*4 + fw]
                   + red[((size_t)w*64 + (lane^8))*21 + r*4 + fw];
              const int x = x0 + q*4 + fw;    // <= 63
              corr_p[(size_t)cb*270400 + ((size_t)(m*8+pr)*65 + (y0 + half*5 + r))*65 + x] = s;
            }
          }
        }
      } else {
        // ======== 5-row tile, rows 60..64 ========
        const int y0 = 60;
        const size_t rowbase = ((size_t)(m*4 + cb) * 96 + y0) * 96;
        for (int k = tid; k < 36*48; k += 256) {
          const int rho = k / 48, px = k - (k/48)*48;
          cp16(&satT[(rowbase + (size_t)rho*96 + x0 + px)*8], &patch[(size_t)k*8]);
        }
        asm volatile("s_waitcnt vmcnt(0)" ::: "memory");
        __syncthreads();

        floatx4 acc[5];
        #pragma unroll
        for (int r = 0; r < 5; ++r) acc[r] = (floatx4){0.f, 0.f, 0.f, 0.f};

        #pragma unroll
        for (int jbi = 0; jbi < 2; ++jbi) {
          const int jb = wave*2 + jbi;
          const int apx = pr + jb*4 + q;
          const u16* bp = gP + ((size_t)cb*1024 + (size_t)(jb*4+q))*128 + (size_t)pr*8;

          uint4 Br[8];
          #pragma unroll
          for (int ii = 0; ii < 8; ++ii) Br[ii] = *(const uint4*)(bp + (size_t)ii*4096);
          uint4 Ah[8];
          #pragma unroll
          for (int s = 0; s < 6; ++s) Ah[s] = *(const uint4*)(&patch[((size_t)s*48 + apx)*8]);

          #pragma unroll
          for (int i = 0; i < 32; ++i) {
            if (i < 30)
              Ah[(i+6)&7] = *(const uint4*)(&patch[((size_t)(i+6)*48 + apx)*8]);
            const bf16x8 bf = __builtin_bit_cast(bf16x8, Br[i&7]);
            if (i < 24)
              Br[(i+8)&7] = *(const uint4*)(bp + (size_t)(i+8)*4096);
            __builtin_amdgcn_s_setprio(1);
            #pragma unroll
            for (int r = 0; r < 5; ++r)
              acc[r] = __builtin_amdgcn_mfma_f32_16x16x32_bf16(
                  __builtin_bit_cast(bf16x8, Ah[(i+r)&7]), bf, acc[r], 0, 0, 0);
            __builtin_amdgcn_s_setprio(0);
          }
        }

        __syncthreads();
        float* red = (float*)patch;
        #pragma unroll
        for (int u = 0; u < 20; ++u)
          red[((size_t)wave*64 + lane)*21 + u] = acc[u>>2][u&3];
        __syncthreads();
        if (pr < 8) {
          const int fw = wave;
          #pragma unroll
          for (int r = 0; r < 5; ++r) {
            float s = 0.f;
            #pragma unroll
            for (int w = 0; w < 4; ++w)
              s += red[((size_t)w*64 + lane)*21 + r*4 + fw]
                 + red[((size_t)w*64 + (lane^8))*21 + r*4 + fw];
            const int x = x0 + q*4 + fw;
            corr_p[(size_t)cb*270400 + ((size_t)(m*8+pr)*65 + (y0+r))*65 + x] = s;
          }
        }
      }
    }

    // ---- next ticket (patch reuse guarded by the barrier pair) ----
    __syncthreads();
    if (tid == 0) s_bi = atomicAdd(tick, 1u);
    __syncthreads();
    bi = s_bi;
    if (bi >= 1128) return;
  }
}

// ---- K3: streaming normalize/max + candidate collect + gmax gather. ----
__global__ __launch_bounds__(256) void k_post(
    const float* __restrict__ corr_p, const float* __restrict__ part,
    const float* __restrict__ nrmp, const float* __restrict__ gnrm,
    const int* __restrict__ tm,
    u32* __restrict__ pmaxE, u32* __restrict__ grpcnt,
    u32* __restrict__ candcnt, u64* __restrict__ cand,
    float* __restrict__ cscN, float* __restrict__ pscN,
    float* __restrict__ out)
{
  __shared__ float red[8];
  __shared__ int s_last;

  const int bi = blockIdx.x;
  const int m = bi / 40, n = (bi / 5) & 7, yc = bi % 5, g = m*8 + n;
  const int t = threadIdx.x;
  const int wv = t >> 6, ln = t & 63;
  const bool diag = (m == n);

  float v0 = (t < 96) ? nrmp[m*96 + t] : 0.f;
  v0 = wred_sum(v0);
  if (ln == 0) red[wv] = v0;
  __syncthreads();
  const float snrm2 = red[0] + red[1] + red[2] + red[3];
  const float srn = 1.f / fmaxf(sqrtf(snrm2), 1e-12f);
  const float grn = 1.f / fmaxf(sqrtf(gnrm[n]), 1e-12f);
  const float cscale = grn * srn, pscale = srn * srn;
  const int method = tm[0];
  if (diag && t == 0) { cscN[n] = cscale; pscN[n] = pscale; }   // for k_refine

  const float* cp = corr_p + (size_t)g*4225;
  const float* pp = part + (size_t)m*4225;
  const int i0 = yc*845, i1 = i0 + 845;
  float vv[4];
  float bestv = -3.4e38f;
  #pragma unroll
  for (int k = 0; k < 4; ++k) {
    const int idx = i0 + k*256 + t;
    float v = -3.4e38f;
    if (idx < i1) {
      const float c = cp[idx] + cp[idx+270400] + cp[idx+540800] + cp[idx+811200];
      const float pt = pp[idx] * pscale;
      float denom = (method == 0) ? sqrtf(pt) : pt;
      denom = fmaxf(denom, 1e-12f);
      v = c * cscale / denom;
    }
    vv[k] = v;
    bestv = fmaxf(bestv, v);
  }
  __syncthreads();                    // red WAR guard
  const float bw = wred_max(bestv);
  if (ln == 0) red[wv] = bw;
  __syncthreads();
  const float bmax = fmaxf(fmaxf(red[0], red[1]), fmaxf(red[2], red[3]));
  if (t == 0) atomicExch(&pmaxE[bi], encf(bmax));

  if (diag) {
    // collect candidate superset: within 3e-3 of BLOCK max (global filter in k_refine)
    const float lthr = bmax - 3e-3f;
    #pragma unroll
    for (int k = 0; k < 4; ++k) {
      const int idx = i0 + k*256 + t;
      if (idx < i1 && vv[k] >= lthr) {
        const u32 s = atomicAdd(&candcnt[n], 1u);
        if (s < 128)
          atomicExch(&cand[n*128 + s],
                     ((u64)__builtin_bit_cast(u32, vv[k]) << 32) | (u32)idx);
      }
    }
  }
  __syncthreads();
  if (t == 0) s_last = (atomicAdd(&grpcnt[g], 1u) == 4u) ? 1 : 0;
  __syncthreads();
  if (!s_last) return;

  if (t < 5) {
    const u32 e = atomicOr(&pmaxE[g*5 + t], 0u);
    const u32 u = (e >> 31) ? (e & 0x7FFFFFFFu) : ~e;
    red[t] = __builtin_bit_cast(float, u);
  }
  __syncthreads();
  const float gmax = fmaxf(fmaxf(fmaxf(red[0], red[1]), fmaxf(red[2], red[3])), red[4]);
  if (t == 0) out[g] = gmax;
}

// ---- K4: parallel refine + mask. 1024 blocks = 8 n x 128 candidate slots.
//      Each active slot computes one exact f32 dot (coalesced, 256 threads),
//      atomicMax's a (value,~idx) key; last slot per n writes the mask.
//      NO __threadfence (R4 lesson: it is an L2 wb/inv storm, +45us). ----
__global__ __launch_bounds__(256) void k_refine(
    const float* __restrict__ part, const int* __restrict__ tm,
    const float* __restrict__ grd, const float* __restrict__ sat,
    const float* __restrict__ gmask,
    const u32* __restrict__ candcnt, const u64* __restrict__ cand,
    const float* __restrict__ cscN, const float* __restrict__ pscN,
    u32* __restrict__ rdone, u64* __restrict__ bestu,
    float* __restrict__ out)
{
  __shared__ float red[4];
  __shared__ int s_last;

  const int bid = blockIdx.x;
  const int n = bid >> 7, ci = bid & 127;
  const int t = threadIdx.x;
  const int wv = t >> 6, ln = t & 63;

  u32 nc = candcnt[n]; if (nc > 128u) nc = 128u;
  bool act = (ci < (int)nc);
  int idx = 0;
  if (act) {
    const u64 pk = cand[n*128 + ci];
    const float vf = __builtin_bit_cast(float, (u32)(pk >> 32));
    idx = (int)(u32)pk;
    act = (vf >= out[9*n] - 3e-3f);     // global filter (gmax from k_post)
  }
  if (act) {
    const int y = idx / 65, x = idx - y*65;
    const int i0 = t >> 5, j = t & 31;   // lanes sweep j: coalesced 128B runs
    const float* gb = grd + (size_t)n*32768 + i0*32 + j;
    const float* sb = sat + (((size_t)n*32*128) + 16 + y + i0)*128 + 16 + x + j;
    float a = 0.f;
    #pragma unroll 4
    for (int c = 0; c < 32; ++c) {
      #pragma unroll
      for (int ii = 0; ii < 4; ++ii)
        a += gb[(size_t)(c*32 + ii*8)*32] * sb[((size_t)c*128 + ii*8)*128];
    }
    a = wred_sum(a);
    if (ln == 0) red[wv] = a;
    __syncthreads();
    if (t == 0) {
      const float tot = red[0] + red[1] + red[2] + red[3];
      const float pt = part[(size_t)n*4225 + idx] * pscN[n];
      float denom = (tm[0] == 0) ? sqrtf(pt) : pt;
      denom = fmaxf(denom, 1e-12f);
      const float v = tot * cscN[n] / denom;
      const u64 key = ((u64)encf(v) << 32) | (u64)(0xFFFFFFFFu - (u32)idx);
      atomicMax(&bestu[n], key);
    }
  }
  __syncthreads();     // drains vmcnt(0): bestu atomicMax committed before rdone
  if (t == 0) s_last = (atomicAdd(&rdone[n], 1u) == 127u) ? 1 : 0;
  __syncthreads();
  if (!s_last) return;

  const u64 bk = atomicAdd(&bestu[n], 0ULL);
  const int bix = (int)(0xFFFFFFFFu - (u32)bk);
  const int ph = bix / 65, pw = bix - (bix/65)*65;
  for (int p = t; p < 9216; p += 256) {
    const int yy = p / 96, xx = p - yy*96;
    float val = 0.f;
    if (yy >= ph && yy < ph+32 && xx >= pw && xx < pw+32)
      val = gmask[n*1024 + (yy-ph)*32 + (xx-pw)];
    out[64 + (size_t)n*9216 + p] = val;
  }
}

extern "C" void kernel_launch(void* const* d_in, const int* in_sizes, int n_in,
                              void* d_out, int out_size, void* d_ws, size_t ws_size,
                              hipStream_t stream) {
  const float* grd = (const float*)d_in[0];
  const float* sat = (const float*)d_in[1];
  const int*   tm  = (const int*)d_in[2];
  float* out = (float*)d_out;
  char* ws = (char*)d_ws;

  float* corrp = (float*)(ws + OFF_CORRP);
  u16*   sTh   = (u16*)(ws + OFF_SATT);
  u16*   gP    = (u16*)(ws + OFF_GRDP);
  float* s2    = (float*)(ws + OFF_S2);
  float* part  = (float*)(ws + OFF_PART);
  float* nrmp  = (float*)(ws + OFF_NRMP);
  float* gnrm  = (float*)(ws + OFF_GNRM);
  float* gmask = (float*)(ws + OFF_MASK);
  u32*   pmaxE = (u32*)(ws + OFF_PMAX);
  u32*   cnts  = (u32*)(ws + OFF_CNT);
  u32*   candcnt = cnts + 64;
  u32*   tick  = cnts + 72;
  u32*   rdone = cnts + 88;
  u64*   bestu = (u64*)(ws + OFF_CNT + 384);
  float* cscN  = (float*)(cnts + 112);
  float* pscN  = (float*)(cnts + 120);
  u64*   cand  = (u64*)(ws + OFF_CAND);

  k_prep<<<777,  256, 0, stream>>>(grd, sat, sTh, gP, s2, nrmp, gnrm, gmask, cnts);
  k_conv<<<1024, 256, 0, stream>>>(sTh, gP, s2, corrp, part, tick);
  k_post<<<320,  256, 0, stream>>>(corrp, part, nrmp, gnrm, tm,
                                   pmaxE, cnts, candcnt, cand, cscN, pscN, out);
  k_refine<<<1024, 256, 0, stream>>>(part, tm, grd, sat, gmask,
                                     candcnt, cand, cscN, pscN,
                                     rdone, bestu, out);
}

// Round 8
// 143.938 us; speedup vs baseline: 1.4571x; 1.0309x over previous
//
#include <hip/hip_runtime.h>
#include <stdint.h>

typedef unsigned short u16;
typedef unsigned int u32;
typedef unsigned long long u64;
typedef __bf16 bf16x8 __attribute__((ext_vector_type(8)));
typedef float floatx4 __attribute__((ext_vector_type(4)));

#define DEVI static __device__ __forceinline__

DEVI u16 f2bf(float f) {
  uint32_t u = __builtin_bit_cast(uint32_t, f);
  u += 0x7FFFu + ((u >> 16) & 1u);
  return (u16)(u >> 16);
}
DEVI float bf2f(u16 b) { return __builtin_bit_cast(float, (uint32_t)b << 16); }

// order-preserving float<->uint encoding
DEVI u32 encf(float f) {
  u32 u = __builtin_bit_cast(u32, f);
  return (u >> 31) ? ~u : (u | 0x80000000u);
}

// 64-lane wave reductions: 6 shuffles, no barriers
DEVI float wred_sum(float v) {
  #pragma unroll
  for (int o = 32; o > 0; o >>= 1) v += __shfl_xor(v, o);
  return v;
}
DEVI float wred_max(float v) {
  #pragma unroll
  for (int o = 32; o > 0; o >>= 1) v = fmaxf(v, __shfl_xor(v, o));
  return v;
}

// async global->LDS 16B (lds dest = wave-uniform base + lane*16)
DEVI void cp16(const u16* g, u16* l) {
#if __has_builtin(__builtin_amdgcn_global_load_lds)
  __builtin_amdgcn_global_load_lds(
      (const __attribute__((address_space(1))) uint32_t*)g,
      (__attribute__((address_space(3))) uint32_t*)l, 16, 0, 0);
#else
  *(uint4*)l = *(const uint4*)g;
#endif
}

// ---- workspace layout (bytes) ----
static constexpr size_t OFF_CORRP = 0;                                   // f32 [cb4][m][n][65][65]
static constexpr size_t OFF_SATT  = OFF_CORRP + (size_t)4*270400*4;      // bf16 [m][cb][y][x][c8]
static constexpr size_t OFF_GRDP  = OFF_SATT + (size_t)8*4*96*96*8*2;    // bf16 [cb][i*32+j][col16][c8]
static constexpr size_t OFF_S2    = OFF_GRDP + (size_t)4*1024*16*8*2;    // f32 [8][96][96]
static constexpr size_t OFF_PART  = OFF_S2   + (size_t)73728*4;          // f32 [8][65][65]
static constexpr size_t OFF_NRMP  = OFF_PART + (size_t)33800*4;          // f32 sat nrm partials [8][96]
static constexpr size_t OFF_GNRM  = OFF_NRMP + 768*4;                    // f32 grd nrm2 [8]
static constexpr size_t OFF_MASK  = OFF_GNRM + 32;                       // f32 [8][1024]
static constexpr size_t OFF_PMAX  = OFF_MASK + (size_t)8192*4;           // u32 enc chunk max [320]
static constexpr size_t OFF_CNT   = OFF_PMAX + 320*4;                    // 512B control block (u32 idx):
//   [0..63] grpcnt  [64..71] candcnt  [72] ticket  [88..95] rdone[8]
//   [96..111] u64 bestu[8] (byte off 384)  [112..119] cscN[8]  [120..127] pscN[8]
static constexpr size_t OFF_CAND  = OFF_CNT  + 512;                      // u64 cand[8][128]

// ---- K1: blocks 0..767: one sat row -> bf16 channels-last + s2 + norm partial.
//          blocks 768..775: grd pack. block 776: zero/seed control block.
__global__ __launch_bounds__(256) void k_prep(
    const float* __restrict__ grd, const float* __restrict__ sat,
    u16* __restrict__ sTh, u16* __restrict__ gP,
    float* __restrict__ s2, float* __restrict__ nrmp,
    float* __restrict__ gnrm, float* __restrict__ gmask,
    u32* __restrict__ cnts) {
  __shared__ float L[32*100];
  __shared__ float red[4];
  const int t = threadIdx.x;
  if (blockIdx.x < 768) {
    const int m = blockIdx.x / 96, y = blockIdx.x - (blockIdx.x / 96) * 96;
    #pragma unroll
    for (int k = 0; k < 3; ++k) {
      const int idx = k*256 + t;
      const int c = idx / 24, xq = idx - c*24;
      const float4 v = *(const float4*)(sat + (((size_t)m*32 + c)*128 + (16+y))*128 + 16 + xq*4);
      *(float4*)(&L[c*100 + xq*4]) = v;
    }
    __syncthreads();
    float ss = 0.f;
    if (t < 96) {
      #pragma unroll
      for (int c = 0; c < 32; ++c) { const float v = L[c*100 + t]; ss += v*v; }
      s2[(size_t)m*9216 + y*96 + t] = ss;
    }
    const float wsum = wred_sum(ss);
    if ((t & 63) == 0) red[t >> 6] = wsum;
    __syncthreads();
    if (t == 0) nrmp[m*96 + y] = red[0] + red[1] + red[2] + red[3];
    for (int idx = t; idx < 384; idx += 256) {
      const int cb = idx / 96, x = idx - cb*96;
      union { u16 us[8]; uint4 v4; } P;
      #pragma unroll
      for (int e = 0; e < 8; ++e) P.us[e] = f2bf(L[(cb*8+e)*100 + x]);
      *(uint4*)(&sTh[(((size_t)m*4+cb)*9216 + (size_t)y*96 + x)*8]) = P.v4;
    }
  } else if (blockIdx.x == 776) {
    // zero grpcnt/candcnt/rdone; ticket=768 (static tiles 0..767); seed
    // bestu[n]=0x00000000FFFFFFFF (=> decoded bix=0 when nothing passes).
    if (t < 112)
      cnts[t] = (t == 72) ? 768u
              : ((t >= 96 && !(t & 1)) ? 0xFFFFFFFFu : 0u);
  } else {
    const int n = blockIdx.x - 768;
    float nn = 0.f, scs[4];
    #pragma unroll
    for (int it = 0; it < 4; ++it) {
      const int pidx = it*256 + t;
      float vals[32]; float sc = 0.f;
      #pragma unroll
      for (int c = 0; c < 32; ++c) {
        const float v = grd[((size_t)n*32 + c)*1024 + pidx];
        vals[c] = v; sc += v; nn += v*v;
      }
      scs[it] = sc;
      #pragma unroll
      for (int cb = 0; cb < 4; ++cb) {
        union { u16 us[8]; uint4 v4; } ph, pl;
        #pragma unroll
        for (int e = 0; e < 8; ++e) {
          const float v = vals[cb*8+e];
          const u16 h = f2bf(v); ph.us[e] = h; pl.us[e] = f2bf(v - bf2f(h));
        }
        const size_t o = ((size_t)cb*1024 + pidx)*128;
        *(uint4*)(&gP[o + (size_t)n*8])     = ph.v4;
        *(uint4*)(&gP[o + (size_t)(n+8)*8]) = pl.v4;
      }
    }
    const float tot = wred_sum(nn);
    if ((t & 63) == 0) red[t >> 6] = tot;
    __syncthreads();
    const float sum = red[0] + red[1] + red[2] + red[3];
    if (t == 0) gnrm[n] = sum;
    const float gn = fmaxf(sqrtf(sum), 1e-12f);
    const float thr = 1e-6f * gn;
    #pragma unroll
    for (int it = 0; it < 4; ++it)
      gmask[n*1024 + it*256 + t] = (fabsf(scs[it]) > thr) ? 1.f : 0.f;
  }
}

// ---- K2: persistent blocks (grid=768, 3/CU — R5-proven optimum) draining
//      1128 tile tickets. tiles 0..71: part windows; 72..967: main conv;
//      968..1127: edge x=64.
//      LB stays (256,3): (256,4) spills (R6: VGPR 84->64, WRITE 10x).
//      grid=1024 adds nothing (R7: 4th block never resident, k_conv identical).
__global__ __launch_bounds__(256, 3) void k_conv(
    const u16* __restrict__ satT, const u16* __restrict__ gP,
    const float* __restrict__ s2, float* __restrict__ corr_p,
    float* __restrict__ part, u32* __restrict__ tick)
{
  __shared__ __align__(16) u16 patch[41*48*8];   // 31488 B
  __shared__ u32 s_bi;

  const int tid = threadIdx.x;
  const int wave = tid >> 6, lane = tid & 63;
  const int pr = lane & 15, q = lane >> 4;

  u32 bi = blockIdx.x;           // first tile static (keeps part tiles first)
  for (;;) {
    if (bi < 72) {               // ---- part tile ----
      float* S  = (float*)patch;          // [<=40][96]
      float* HS = S + 40*96;              // [<=39][65]
      const int pm = (int)bi / 9, ysl = ((int)bi - pm*9)*8;
      const int nrows = (65 - ysl) < 8 ? (65 - ysl) : 8;
      const int scnt  = (96 - ysl) < 40 ? (96 - ysl) : 40;
      for (int idx = tid; idx < scnt*96; idx += 256)
        S[idx] = s2[(size_t)pm*9216 + (size_t)ysl*96 + idx];
      __syncthreads();
      const int hrows = nrows + 31;
      for (int idx = tid; idx < hrows*65; idx += 256) {
        const int r = idx / 65, xo = idx - r*65;
        const float* p = &S[r*96 + xo];
        float s = 0.f;
        #pragma unroll
        for (int j = 0; j < 32; ++j) s += p[j];
        HS[idx] = s;
      }
      __syncthreads();
      for (int idx = tid; idx < nrows*65; idx += 256) {
        const int r = idx / 65, xo = idx - r*65;
        float s = 0.f;
        #pragma unroll
        for (int i = 0; i < 32; ++i) s += HS[(r+i)*65 + xo];
        part[(size_t)pm*4225 + (size_t)(ysl+r)*65 + xo] = s;
      }
    } else if (bi >= 968) {      // ---- edge tile: x = 64 column ----
      const int e = (int)bi - 968;
      const int cb = e & 3;
      const int yt = (e >> 2) % 5;
      const int m  = e / 20;
      const int ybase = yt * 13;
      const size_t rowbase = ((size_t)(m*4 + cb) * 96 + ybase) * 96;
      for (int k = tid; k < 44*32; k += 256) {
        const int rho = k >> 5, px = k & 31;
        cp16(&satT[(rowbase + (size_t)rho*96 + 64 + px)*8], &patch[(size_t)k*8]);
      }
      asm volatile("s_waitcnt vmcnt(0)" ::: "memory");
      __syncthreads();
      const int prc = pr < 13 ? pr : 12;   // rows 13-15 duplicate row 12
      floatx4 acc = (floatx4){0.f, 0.f, 0.f, 0.f};
      #pragma unroll
      for (int jbi = 0; jbi < 2; ++jbi) {
        const int jb = wave*2 + jbi;
        const int px_e = jb*4 + q;
        const u16* bp = gP + ((size_t)cb*1024 + (size_t)(jb*4+q))*128 + (size_t)pr*8;
        uint4 Br[8];
        #pragma unroll
        for (int ii = 0; ii < 8; ++ii) Br[ii] = *(const uint4*)(bp + (size_t)ii*4096);
        uint4 Ah[8];
        #pragma unroll
        for (int s = 0; s < 6; ++s)
          Ah[s] = *(const uint4*)(&patch[((size_t)(prc + s)*32 + px_e)*8]);
        #pragma unroll
        for (int i = 0; i < 32; ++i) {
          if (i < 26)
            Ah[(i+6)&7] = *(const uint4*)(&patch[((size_t)(prc + i + 6)*32 + px_e)*8]);
          const bf16x8 bf = __builtin_bit_cast(bf16x8, Br[i&7]);
          if (i < 24)
            Br[(i+8)&7] = *(const uint4*)(bp + (size_t)(i+8)*4096);
          acc = __builtin_amdgcn_mfma_f32_16x16x32_bf16(
              __builtin_bit_cast(bf16x8, Ah[i&7]), bf, acc, 0, 0, 0);
        }
      }
      float v4[4];
      #pragma unroll
      for (int k = 0; k < 4; ++k) v4[k] = acc[k] + __shfl_xor(acc[k], 8);
      __syncthreads();
      float* red = (float*)patch;
      #pragma unroll
      for (int k = 0; k < 4; ++k) red[((size_t)wave*64 + lane)*5 + k] = v4[k];
      __syncthreads();
      if (wave == 0 && pr < 8) {
        #pragma unroll
        for (int k = 0; k < 4; ++k) {
          const int yoff = q*4 + k;
          if (yoff < 13) {
            float s = 0.f;
            #pragma unroll
            for (int w = 0; w < 4; ++w) s += red[((size_t)w*64 + lane)*5 + k];
            corr_p[(size_t)cb*270400 + ((size_t)(m*8+pr)*65 + (ybase+yoff))*65 + 64] = s;
          }
        }
      }
    } else {                     // ---- main conv tile ----
      int bb = (int)bi - 72;
      const int cb = bb & 3; bb >>= 2;
      const int xt = bb & 3; bb >>= 2;
      const int yt = bb % 7;
      const int m  = bb / 7;
      const int x0 = xt*16;

      if (yt < 6) {
        // ======== 10-row tile, rows y0..y0+9, patch 41 rows ========
        const int y0 = yt*10;
        const size_t rowbase = ((size_t)(m*4 + cb) * 96 + y0) * 96;
        for (int k = tid; k < 41*48; k += 256) {
          const int rho = k / 48, px = k - (k/48)*48;
          cp16(&satT[(rowbase + (size_t)rho*96 + x0 + px)*8], &patch[(size_t)k*8]);
        }
        asm volatile("s_waitcnt vmcnt(0)" ::: "memory");
        __syncthreads();

        floatx4 acc[10];
        #pragma unroll
        for (int r = 0; r < 10; ++r) acc[r] = (floatx4){0.f, 0.f, 0.f, 0.f};

        #pragma unroll
        for (int jbi = 0; jbi < 2; ++jbi) {
          const int jb = wave*2 + jbi;
          const int apx = pr + jb*4 + q;                       // <= 46
          const u16* bp = gP + ((size_t)cb*1024 + (size_t)(jb*4+q))*128 + (size_t)pr*8;

          uint4 Br[8];
          #pragma unroll
          for (int ii = 0; ii < 8; ++ii) Br[ii] = *(const uint4*)(bp + (size_t)ii*4096);
          uint4 Ah[12];
          #pragma unroll
          for (int s = 0; s < 12; ++s) Ah[s] = *(const uint4*)(&patch[((size_t)s*48 + apx)*8]);

          #pragma unroll
          for (int i = 0; i < 32; ++i) {
            const bf16x8 bf = __builtin_bit_cast(bf16x8, Br[i&7]);
            if (i < 24)
              Br[(i+8)&7] = *(const uint4*)(bp + (size_t)(i+8)*4096);
            __builtin_amdgcn_s_setprio(1);
            #pragma unroll
            for (int r = 0; r < 10; ++r)
              acc[r] = __builtin_amdgcn_mfma_f32_16x16x32_bf16(
                  __builtin_bit_cast(bf16x8, Ah[(i+r)%12]), bf, acc[r], 0, 0, 0);
            __builtin_amdgcn_s_setprio(0);
            if (i < 29)
              Ah[(i+12)%12] = *(const uint4*)(&patch[((size_t)(i+12)*48 + apx)*8]);
          }
        }

        float* red = (float*)patch;
        #pragma unroll
        for (int half = 0; half < 2; ++half) {
          __syncthreads();
          #pragma unroll
          for (int u = 0; u < 20; ++u)
            red[((size_t)wave*64 + lane)*21 + u] = acc[half*5 + (u>>2)][u&3];
          __syncthreads();
          if (pr < 8) {
            const int fw = wave;
            #pragma unroll
            for (int r = 0; r < 5; ++r) {
              float s = 0.f;
              #pragma unroll
              for (int w = 0; w < 4; ++w)
                s += red[((size_t)w*64 + lane)*21 + r*4 + fw]
                   + red[((size_t)w*64 + (lane^8))*21 + r*4 + fw];
              const int x = x0 + q*4 + fw;    // <= 63
              corr_p[(size_t)cb*270400 + ((size_t)(m*8+pr)*65 + (y0 + half*5 + r))*65 + x] = s;
            }
          }
        }
      } else {
        // ======== 5-row tile, rows 60..64 ========
        const int y0 = 60;
        const size_t rowbase = ((size_t)(m*4 + cb) * 96 + y0) * 96;
        for (int k = tid; k < 36*48; k += 256) {
          const int rho = k / 48, px = k - (k/48)*48;
          cp16(&satT[(rowbase + (size_t)rho*96 + x0 + px)*8], &patch[(size_t)k*8]);
        }
        asm volatile("s_waitcnt vmcnt(0)" ::: "memory");
        __syncthreads();

        floatx4 acc[5];
        #pragma unroll
        for (int r = 0; r < 5; ++r) acc[r] = (floatx4){0.f, 0.f, 0.f, 0.f};

        #pragma unroll
        for (int jbi = 0; jbi < 2; ++jbi) {
          const int jb = wave*2 + jbi;
          const int apx = pr + jb*4 + q;
          const u16* bp = gP + ((size_t)cb*1024 + (size_t)(jb*4+q))*128 + (size_t)pr*8;

          uint4 Br[8];
          #pragma unroll
          for (int ii = 0; ii < 8; ++ii) Br[ii] = *(const uint4*)(bp + (size_t)ii*4096);
          uint4 Ah[8];
          #pragma unroll
          for (int s = 0; s < 6; ++s) Ah[s] = *(const uint4*)(&patch[((size_t)s*48 + apx)*8]);

          #pragma unroll
          for (int i = 0; i < 32; ++i) {
            if (i < 30)
              Ah[(i+6)&7] = *(const uint4*)(&patch[((size_t)(i+6)*48 + apx)*8]);
            const bf16x8 bf = __builtin_bit_cast(bf16x8, Br[i&7]);
            if (i < 24)
              Br[(i+8)&7] = *(const uint4*)(bp + (size_t)(i+8)*4096);
            __builtin_amdgcn_s_setprio(1);
            #pragma unroll
            for (int r = 0; r < 5; ++r)
              acc[r] = __builtin_amdgcn_mfma_f32_16x16x32_bf16(
                  __builtin_bit_cast(bf16x8, Ah[(i+r)&7]), bf, acc[r], 0, 0, 0);
            __builtin_amdgcn_s_setprio(0);
          }
        }

        __syncthreads();
        float* red = (float*)patch;
        #pragma unroll
        for (int u = 0; u < 20; ++u)
          red[((size_t)wave*64 + lane)*21 + u] = acc[u>>2][u&3];
        __syncthreads();
        if (pr < 8) {
          const int fw = wave;
          #pragma unroll
          for (int r = 0; r < 5; ++r) {
            float s = 0.f;
            #pragma unroll
            for (int w = 0; w < 4; ++w)
              s += red[((size_t)w*64 + lane)*21 + r*4 + fw]
                 + red[((size_t)w*64 + (lane^8))*21 + r*4 + fw];
            const int x = x0 + q*4 + fw;
            corr_p[(size_t)cb*270400 + ((size_t)(m*8+pr)*65 + (y0+r))*65 + x] = s;
          }
        }
      }
    }

    // ---- next ticket (patch reuse guarded by the barrier pair) ----
    __syncthreads();
    if (tid == 0) s_bi = atomicAdd(tick, 1u);
    __syncthreads();
    bi = s_bi;
    if (bi >= 1128) return;
  }
}

// ---- K3: streaming normalize/max + candidate collect + gmax gather. ----
__global__ __launch_bounds__(256) void k_post(
    const float* __restrict__ corr_p, const float* __restrict__ part,
    const float* __restrict__ nrmp, const float* __restrict__ gnrm,
    const int* __restrict__ tm,
    u32* __restrict__ pmaxE, u32* __restrict__ grpcnt,
    u32* __restrict__ candcnt, u64* __restrict__ cand,
    float* __restrict__ cscN, float* __restrict__ pscN,
    float* __restrict__ out)
{
  __shared__ float red[8];
  __shared__ int s_last;

  const int bi = blockIdx.x;
  const int m = bi / 40, n = (bi / 5) & 7, yc = bi % 5, g = m*8 + n;
  const int t = threadIdx.x;
  const int wv = t >> 6, ln = t & 63;
  const bool diag = (m == n);

  float v0 = (t < 96) ? nrmp[m*96 + t] : 0.f;
  v0 = wred_sum(v0);
  if (ln == 0) red[wv] = v0;
  __syncthreads();
  const float snrm2 = red[0] + red[1] + red[2] + red[3];
  const float srn = 1.f / fmaxf(sqrtf(snrm2), 1e-12f);
  const float grn = 1.f / fmaxf(sqrtf(gnrm[n]), 1e-12f);
  const float cscale = grn * srn, pscale = srn * srn;
  const int method = tm[0];
  if (diag && t == 0) { cscN[n] = cscale; pscN[n] = pscale; }   // for k_refine

  const float* cp = corr_p + (size_t)g*4225;
  const float* pp = part + (size_t)m*4225;
  const int i0 = yc*845, i1 = i0 + 845;
  float vv[4];
  float bestv = -3.4e38f;
  #pragma unroll
  for (int k = 0; k < 4; ++k) {
    const int idx = i0 + k*256 + t;
    float v = -3.4e38f;
    if (idx < i1) {
      const float c = cp[idx] + cp[idx+270400] + cp[idx+540800] + cp[idx+811200];
      const float pt = pp[idx] * pscale;
      float denom = (method == 0) ? sqrtf(pt) : pt;
      denom = fmaxf(denom, 1e-12f);
      v = c * cscale / denom;
    }
    vv[k] = v;
    bestv = fmaxf(bestv, v);
  }
  __syncthreads();                    // red WAR guard
  const float bw = wred_max(bestv);
  if (ln == 0) red[wv] = bw;
  __syncthreads();
  const float bmax = fmaxf(fmaxf(red[0], red[1]), fmaxf(red[2], red[3]));
  if (t == 0) atomicExch(&pmaxE[bi], encf(bmax));

  if (diag) {
    // collect candidate superset: within 3e-3 of BLOCK max (global filter in k_refine)
    const float lthr = bmax - 3e-3f;
    #pragma unroll
    for (int k = 0; k < 4; ++k) {
      const int idx = i0 + k*256 + t;
      if (idx < i1 && vv[k] >= lthr) {
        const u32 s = atomicAdd(&candcnt[n], 1u);
        if (s < 128)
          atomicExch(&cand[n*128 + s],
                     ((u64)__builtin_bit_cast(u32, vv[k]) << 32) | (u32)idx);
      }
    }
  }
  __syncthreads();
  if (t == 0) s_last = (atomicAdd(&grpcnt[g], 1u) == 4u) ? 1 : 0;
  __syncthreads();
  if (!s_last) return;

  if (t < 5) {
    const u32 e = atomicOr(&pmaxE[g*5 + t], 0u);
    const u32 u = (e >> 31) ? (e & 0x7FFFFFFFu) : ~e;
    red[t] = __builtin_bit_cast(float, u);
  }
  __syncthreads();
  const float gmax = fmaxf(fmaxf(fmaxf(red[0], red[1]), fmaxf(red[2], red[3])), red[4]);
  if (t == 0) out[g] = gmax;
}

// ---- K4: parallel refine + mask. 1024 blocks = 8 n x 128 candidate slots.
//      Each active slot computes one exact f32 dot (coalesced, 256 threads),
//      atomicMax's a (value,~idx) key; last slot per n writes the mask.
//      NO __threadfence (R4 lesson: it is an L2 wb/inv storm, +45us). ----
__global__ __launch_bounds__(256) void k_refine(
    const float* __restrict__ part, const int* __restrict__ tm,
    const float* __restrict__ grd, const float* __restrict__ sat,
    const float* __restrict__ gmask,
    const u32* __restrict__ candcnt, const u64* __restrict__ cand,
    const float* __restrict__ cscN, const float* __restrict__ pscN,
    u32* __restrict__ rdone, u64* __restrict__ bestu,
    float* __restrict__ out)
{
  __shared__ float red[4];
  __shared__ int s_last;

  const int bid = blockIdx.x;
  const int n = bid >> 7, ci = bid & 127;
  const int t = threadIdx.x;
  const int wv = t >> 6, ln = t & 63;

  u32 nc = candcnt[n]; if (nc > 128u) nc = 128u;
  bool act = (ci < (int)nc);
  int idx = 0;
  if (act) {
    const u64 pk = cand[n*128 + ci];
    const float vf = __builtin_bit_cast(float, (u32)(pk >> 32));
    idx = (int)(u32)pk;
    act = (vf >= out[9*n] - 3e-3f);     // global filter (gmax from k_post)
  }
  if (act) {
    const int y = idx / 65, x = idx - y*65;
    const int i0 = t >> 5, j = t & 31;   // lanes sweep j: coalesced 128B runs
    const float* gb = grd + (size_t)n*32768 + i0*32 + j;
    const float* sb = sat + (((size_t)n*32*128) + 16 + y + i0)*128 + 16 + x + j;
    float a = 0.f;
    #pragma unroll 4
    for (int c = 0; c < 32; ++c) {
      #pragma unroll
      for (int ii = 0; ii < 4; ++ii)
        a += gb[(size_t)(c*32 + ii*8)*32] * sb[((size_t)c*128 + ii*8)*128];
    }
    a = wred_sum(a);
    if (ln == 0) red[wv] = a;
    __syncthreads();
    if (t == 0) {
      const float tot = red[0] + red[1] + red[2] + red[3];
      const float pt = part[(size_t)n*4225 + idx] * pscN[n];
      float denom = (tm[0] == 0) ? sqrtf(pt) : pt;
      denom = fmaxf(denom, 1e-12f);
      const float v = tot * cscN[n] / denom;
      const u64 key = ((u64)encf(v) << 32) | (u64)(0xFFFFFFFFu - (u32)idx);
      atomicMax(&bestu[n], key);
    }
  }
  __syncthreads();     // drains vmcnt(0): bestu atomicMax committed before rdone
  if (t == 0) s_last = (atomicAdd(&rdone[n], 1u) == 127u) ? 1 : 0;
  __syncthreads();
  if (!s_last) return;

  const u64 bk = atomicAdd(&bestu[n], 0ULL);
  const int bix = (int)(0xFFFFFFFFu - (u32)bk);
  const int ph = bix / 65, pw = bix - (bix/65)*65;
  for (int p = t; p < 9216; p += 256) {
    const int yy = p / 96, xx = p - yy*96;
    float val = 0.f;
    if (yy >= ph && yy < ph+32 && xx >= pw && xx < pw+32)
      val = gmask[n*1024 + (yy-ph)*32 + (xx-pw)];
    out[64 + (size_t)n*9216 + p] = val;
  }
}

extern "C" void kernel_launch(void* const* d_in, const int* in_sizes, int n_in,
                              void* d_out, int out_size, void* d_ws, size_t ws_size,
                              hipStream_t stream) {
  const float* grd = (const float*)d_in[0];
  const float* sat = (const float*)d_in[1];
  const int*   tm  = (const int*)d_in[2];
  float* out = (float*)d_out;
  char* ws = (char*)d_ws;

  float* corrp = (float*)(ws + OFF_CORRP);
  u16*   sTh   = (u16*)(ws + OFF_SATT);
  u16*   gP    = (u16*)(ws + OFF_GRDP);
  float* s2    = (float*)(ws + OFF_S2);
  float* part  = (float*)(ws + OFF_PART);
  float* nrmp  = (float*)(ws + OFF_NRMP);
  float* gnrm  = (float*)(ws + OFF_GNRM);
  float* gmask = (float*)(ws + OFF_MASK);
  u32*   pmaxE = (u32*)(ws + OFF_PMAX);
  u32*   cnts  = (u32*)(ws + OFF_CNT);
  u32*   candcnt = cnts + 64;
  u32*   tick  = cnts + 72;
  u32*   rdone = cnts + 88;
  u64*   bestu = (u64*)(ws + OFF_CNT + 384);
  float* cscN  = (float*)(cnts + 112);
  float* pscN  = (float*)(cnts + 120);
  u64*   cand  = (u64*)(ws + OFF_CAND);

  k_prep<<<777, 256, 0, stream>>>(grd, sat, sTh, gP, s2, nrmp, gnrm, gmask, cnts);
  k_conv<<<768, 256, 0, stream>>>(sTh, gP, s2, corrp, part, tick);
  k_post<<<320, 256, 0, stream>>>(corrp, part, nrmp, gnrm, tm,
                                  pmaxE, cnts, candcnt, cand, cscN, pscN, out);
  k_refine<<<1024, 256, 0, stream>>>(part, tm, grd, sat, gmask,
                                     candcnt, cand, cscN, pscN,
                                     rdone, bestu, out);
}

// Round 11
// 143.858 us; speedup vs baseline: 1.4579x; 1.0006x over previous
//
#include <hip/hip_runtime.h>
#include <stdint.h>

typedef unsigned short u16;
typedef unsigned int u32;
typedef unsigned long long u64;
typedef __bf16 bf16x8 __attribute__((ext_vector_type(8)));
typedef float floatx4 __attribute__((ext_vector_type(4)));

#define DEVI static __device__ __forceinline__

DEVI u16 f2bf(float f) {
  uint32_t u = __builtin_bit_cast(uint32_t, f);
  u += 0x7FFFu + ((u >> 16) & 1u);
  return (u16)(u >> 16);
}
DEVI float bf2f(u16 b) { return __builtin_bit_cast(float, (uint32_t)b << 16); }

// order-preserving float<->uint encoding
DEVI u32 encf(float f) {
  u32 u = __builtin_bit_cast(u32, f);
  return (u >> 31) ? ~u : (u | 0x80000000u);
}

// 64-lane wave reductions: 6 shuffles, no barriers
DEVI float wred_sum(float v) {
  #pragma unroll
  for (int o = 32; o > 0; o >>= 1) v += __shfl_xor(v, o);
  return v;
}
DEVI float wred_max(float v) {
  #pragma unroll
  for (int o = 32; o > 0; o >>= 1) v = fmaxf(v, __shfl_xor(v, o));
  return v;
}

// async global->LDS 16B (lds dest = wave-uniform base + lane*16)
DEVI void cp16(const u16* g, u16* l) {
#if __has_builtin(__builtin_amdgcn_global_load_lds)
  __builtin_amdgcn_global_load_lds(
      (const __attribute__((address_space(1))) uint32_t*)g,
      (__attribute__((address_space(3))) uint32_t*)l, 16, 0, 0);
#else
  *(uint4*)l = *(const uint4*)g;
#endif
}

// ---- workspace layout (bytes) ----
static constexpr size_t OFF_CORRP = 0;                                   // f32 [cb4][m][n][65][65]
static constexpr size_t OFF_SATT  = OFF_CORRP + (size_t)4*270400*4;      // bf16 [m][cb][y][x][c8]
static constexpr size_t OFF_GRDP  = OFF_SATT + (size_t)8*4*96*96*8*2;    // bf16 [cb][i*32+j][col16][c8]
static constexpr size_t OFF_S2    = OFF_GRDP + (size_t)4*1024*16*8*2;    // f32 [8][96][96]
static constexpr size_t OFF_PART  = OFF_S2   + (size_t)73728*4;          // f32 [8][65][65]
static constexpr size_t OFF_NRMP  = OFF_PART + (size_t)33800*4;          // f32 sat nrm partials [8][96]
static constexpr size_t OFF_GNRM  = OFF_NRMP + 768*4;                    // f32 grd nrm2 [8]
static constexpr size_t OFF_MASK  = OFF_GNRM + 32;                       // f32 [8][1024]
static constexpr size_t OFF_PMAX  = OFF_MASK + (size_t)8192*4;           // u32 enc chunk max [320]
static constexpr size_t OFF_CNT   = OFF_PMAX + 320*4;                    // 512B control block (u32 idx):
//   [0..63] grpcnt  [64..71] candcnt  [72] (unused)  [88..95] rdone[8]
//   [96..111] u64 bestu[8] (byte off 384)  [112..119] cscN[8]  [120..127] pscN[8]
static constexpr size_t OFF_CAND  = OFF_CNT  + 512;                      // u64 cand[8][128]

// ---- K1: blocks 0..767: one sat row -> bf16 channels-last + s2 + norm partial.
//          blocks 768..775: grd pack. block 776: zero/seed control block.
__global__ __launch_bounds__(256) void k_prep(
    const float* __restrict__ grd, const float* __restrict__ sat,
    u16* __restrict__ sTh, u16* __restrict__ gP,
    float* __restrict__ s2, float* __restrict__ nrmp,
    float* __restrict__ gnrm, float* __restrict__ gmask,
    u32* __restrict__ cnts) {
  __shared__ float L[32*100];
  __shared__ float red[4];
  const int t = threadIdx.x;
  if (blockIdx.x < 768) {
    const int m = blockIdx.x / 96, y = blockIdx.x - (blockIdx.x / 96) * 96;
    #pragma unroll
    for (int k = 0; k < 3; ++k) {
      const int idx = k*256 + t;
      const int c = idx / 24, xq = idx - c*24;
      const float4 v = *(const float4*)(sat + (((size_t)m*32 + c)*128 + (16+y))*128 + 16 + xq*4);
      *(float4*)(&L[c*100 + xq*4]) = v;
    }
    __syncthreads();
    float ss = 0.f;
    if (t < 96) {
      #pragma unroll
      for (int c = 0; c < 32; ++c) { const float v = L[c*100 + t]; ss += v*v; }
      s2[(size_t)m*9216 + y*96 + t] = ss;
    }
    const float wsum = wred_sum(ss);
    if ((t & 63) == 0) red[t >> 6] = wsum;
    __syncthreads();
    if (t == 0) nrmp[m*96 + y] = red[0] + red[1] + red[2] + red[3];
    for (int idx = t; idx < 384; idx += 256) {
      const int cb = idx / 96, x = idx - cb*96;
      union { u16 us[8]; uint4 v4; } P;
      #pragma unroll
      for (int e = 0; e < 8; ++e) P.us[e] = f2bf(L[(cb*8+e)*100 + x]);
      *(uint4*)(&sTh[(((size_t)m*4+cb)*9216 + (size_t)y*96 + x)*8]) = P.v4;
    }
  } else if (blockIdx.x == 776) {
    // zero grpcnt/candcnt/rdone; seed bestu[n]=0x00000000FFFFFFFF
    // (=> decoded bix=0 when no candidate passes; any real key wins).
    if (t < 112)
      cnts[t] = (t >= 96 && !(t & 1)) ? 0xFFFFFFFFu : 0u;
  } else {
    const int n = blockIdx.x - 768;
    float nn = 0.f, scs[4];
    #pragma unroll
    for (int it = 0; it < 4; ++it) {
      const int pidx = it*256 + t;
      float vals[32]; float sc = 0.f;
      #pragma unroll
      for (int c = 0; c < 32; ++c) {
        const float v = grd[((size_t)n*32 + c)*1024 + pidx];
        vals[c] = v; sc += v; nn += v*v;
      }
      scs[it] = sc;
      #pragma unroll
      for (int cb = 0; cb < 4; ++cb) {
        union { u16 us[8]; uint4 v4; } ph, pl;
        #pragma unroll
        for (int e = 0; e < 8; ++e) {
          const float v = vals[cb*8+e];
          const u16 h = f2bf(v); ph.us[e] = h; pl.us[e] = f2bf(v - bf2f(h));
        }
        const size_t o = ((size_t)cb*1024 + pidx)*128;
        *(uint4*)(&gP[o + (size_t)n*8])     = ph.v4;
        *(uint4*)(&gP[o + (size_t)(n+8)*8]) = pl.v4;
      }
    }
    const float tot = wred_sum(nn);
    if ((t & 63) == 0) red[t >> 6] = tot;
    __syncthreads();
    const float sum = red[0] + red[1] + red[2] + red[3];
    if (t == 0) gnrm[n] = sum;
    const float gn = fmaxf(sqrtf(sum), 1e-12f);
    const float thr = 1e-6f * gn;
    #pragma unroll
    for (int it = 0; it < 4; ++it)
      gmask[n*1024 + it*256 + t] = (fabsf(scs[it]) > thr) ? 1.f : 0.f;
  }
}

// ---- K2: STATIC grid 1128 (R1-proven: ticket/persistent variant measured
//      +3-5us slower in R5-R8 — 2 extra barriers + cross-XCD atomic per tile
//      for ~1.5 tiles/block of balancing). blocks 0..71: part windows (first,
//      off the critical tail); 72..967: main conv; 968..1127: edge x=64.
__global__ __launch_bounds__(256, 3) void k_conv(
    const u16* __restrict__ satT, const u16* __restrict__ gP,
    const float* __restrict__ s2, float* __restrict__ corr_p,
    float* __restrict__ part)
{
  __shared__ __align__(16) u16 patch[41*48*8];   // 31488 B

  const int bi = blockIdx.x;
  const int tid = threadIdx.x;

  if (bi < 72) {               // ---- part blocks ----
    float* S  = (float*)patch;          // [<=40][96]
    float* HS = S + 40*96;              // [<=39][65]
    const int pm = bi / 9, ysl = (bi - pm*9)*8;
    const int nrows = (65 - ysl) < 8 ? (65 - ysl) : 8;
    const int scnt  = (96 - ysl) < 40 ? (96 - ysl) : 40;
    for (int idx = tid; idx < scnt*96; idx += 256)
      S[idx] = s2[(size_t)pm*9216 + (size_t)ysl*96 + idx];
    __syncthreads();
    const int hrows = nrows + 31;
    for (int idx = tid; idx < hrows*65; idx += 256) {
      const int r = idx / 65, xo = idx - r*65;
      const float* p = &S[r*96 + xo];
      float s = 0.f;
      #pragma unroll
      for (int j = 0; j < 32; ++j) s += p[j];
      HS[idx] = s;
    }
    __syncthreads();
    for (int idx = tid; idx < nrows*65; idx += 256) {
      const int r = idx / 65, xo = idx - r*65;
      float s = 0.f;
      #pragma unroll
      for (int i = 0; i < 32; ++i) s += HS[(r+i)*65 + xo];
      part[(size_t)pm*4225 + (size_t)(ysl+r)*65 + xo] = s;
    }
    return;
  }

  const int wave = tid >> 6, lane = tid & 63;
  const int pr = lane & 15, q = lane >> 4;

  if (bi >= 968) {             // ---- edge blocks: x = 64 column ----
    const int e = bi - 968;
    const int cb = e & 3;
    const int yt = (e >> 2) % 5;
    const int m  = e / 20;
    const int ybase = yt * 13;
    const size_t rowbase = ((size_t)(m*4 + cb) * 96 + ybase) * 96;
    for (int k = tid; k < 44*32; k += 256) {
      const int rho = k >> 5, px = k & 31;
      cp16(&satT[(rowbase + (size_t)rho*96 + 64 + px)*8], &patch[(size_t)k*8]);
    }
    asm volatile("s_waitcnt vmcnt(0)" ::: "memory");
    __syncthreads();
    const int prc = pr < 13 ? pr : 12;   // rows 13-15 duplicate row 12
    floatx4 acc = (floatx4){0.f, 0.f, 0.f, 0.f};
    #pragma unroll
    for (int jbi = 0; jbi < 2; ++jbi) {
      const int jb = wave*2 + jbi;
      const int px_e = jb*4 + q;
      const u16* bp = gP + ((size_t)cb*1024 + (size_t)(jb*4+q))*128 + (size_t)pr*8;
      uint4 Br[8];
      #pragma unroll
      for (int ii = 0; ii < 8; ++ii) Br[ii] = *(const uint4*)(bp + (size_t)ii*4096);
      uint4 Ah[8];
      #pragma unroll
      for (int s = 0; s < 6; ++s)
        Ah[s] = *(const uint4*)(&patch[((size_t)(prc + s)*32 + px_e)*8]);
      #pragma unroll
      for (int i = 0; i < 32; ++i) {
        if (i < 26)
          Ah[(i+6)&7] = *(const uint4*)(&patch[((size_t)(prc + i + 6)*32 + px_e)*8]);
        const bf16x8 bf = __builtin_bit_cast(bf16x8, Br[i&7]);
        if (i < 24)
          Br[(i+8)&7] = *(const uint4*)(bp + (size_t)(i+8)*4096);
        acc = __builtin_amdgcn_mfma_f32_16x16x32_bf16(
            __builtin_bit_cast(bf16x8, Ah[i&7]), bf, acc, 0, 0, 0);
      }
    }
    float v4[4];
    #pragma unroll
    for (int k = 0; k < 4; ++k) v4[k] = acc[k] + __shfl_xor(acc[k], 8);
    __syncthreads();
    float* red = (float*)patch;
    #pragma unroll
    for (int k = 0; k < 4; ++k) red[((size_t)wave*64 + lane)*5 + k] = v4[k];
    __syncthreads();
    if (wave == 0 && pr < 8) {
      #pragma unroll
      for (int k = 0; k < 4; ++k) {
        const int yoff = q*4 + k;
        if (yoff < 13) {
          float s = 0.f;
          #pragma unroll
          for (int w = 0; w < 4; ++w) s += red[((size_t)w*64 + lane)*5 + k];
          corr_p[(size_t)cb*270400 + ((size_t)(m*8+pr)*65 + (ybase+yoff))*65 + 64] = s;
        }
      }
    }
    return;
  }

  // ---- main conv blocks ----
  int b = bi - 72;
  const int cb = b & 3; b >>= 2;
  const int xt = b & 3; b >>= 2;
  const int yt = b % 7;
  const int m  = b / 7;
  const int x0 = xt*16;

  if (yt < 6) {
    // ======== 10-row tile, rows y0..y0+9, patch 41 rows ========
    const int y0 = yt*10;
    const size_t rowbase = ((size_t)(m*4 + cb) * 96 + y0) * 96;
    for (int k = tid; k < 41*48; k += 256) {
      const int rho = k / 48, px = k - (k/48)*48;
      cp16(&satT[(rowbase + (size_t)rho*96 + x0 + px)*8], &patch[(size_t)k*8]);
    }
    asm volatile("s_waitcnt vmcnt(0)" ::: "memory");
    __syncthreads();

    floatx4 acc[10];
    #pragma unroll
    for (int r = 0; r < 10; ++r) acc[r] = (floatx4){0.f, 0.f, 0.f, 0.f};

    #pragma unroll
    for (int jbi = 0; jbi < 2; ++jbi) {
      const int jb = wave*2 + jbi;
      const int apx = pr + jb*4 + q;                       // <= 46
      const u16* bp = gP + ((size_t)cb*1024 + (size_t)(jb*4+q))*128 + (size_t)pr*8;

      uint4 Br[8];
      #pragma unroll
      for (int ii = 0; ii < 8; ++ii) Br[ii] = *(const uint4*)(bp + (size_t)ii*4096);
      uint4 Ah[12];
      #pragma unroll
      for (int s = 0; s < 12; ++s) Ah[s] = *(const uint4*)(&patch[((size_t)s*48 + apx)*8]);

      #pragma unroll
      for (int i = 0; i < 32; ++i) {
        const bf16x8 bf = __builtin_bit_cast(bf16x8, Br[i&7]);
        if (i < 24)
          Br[(i+8)&7] = *(const uint4*)(bp + (size_t)(i+8)*4096);
        __builtin_amdgcn_s_setprio(1);
        #pragma unroll
        for (int r = 0; r < 10; ++r)
          acc[r] = __builtin_amdgcn_mfma_f32_16x16x32_bf16(
              __builtin_bit_cast(bf16x8, Ah[(i+r)%12]), bf, acc[r], 0, 0, 0);
        __builtin_amdgcn_s_setprio(0);
        if (i < 29)
          Ah[(i+12)%12] = *(const uint4*)(&patch[((size_t)(i+12)*48 + apx)*8]);
      }
    }

    float* red = (float*)patch;
    #pragma unroll
    for (int half = 0; half < 2; ++half) {
      __syncthreads();
      #pragma unroll
      for (int u = 0; u < 20; ++u)
        red[((size_t)wave*64 + lane)*21 + u] = acc[half*5 + (u>>2)][u&3];
      __syncthreads();
      if (pr < 8) {
        const int fw = wave;
        #pragma unroll
        for (int r = 0; r < 5; ++r) {
          float s = 0.f;
          #pragma unroll
          for (int w = 0; w < 4; ++w)
            s += red[((size_t)w*64 + lane)*21 + r*4 + fw]
               + red[((size_t)w*64 + (lane^8))*21 + r*4 + fw];
          const int x = x0 + q*4 + fw;    // <= 63
          corr_p[(size_t)cb*270400 + ((size_t)(m*8+pr)*65 + (y0 + half*5 + r))*65 + x] = s;
        }
      }
    }
  } else {
    // ======== 5-row tile, rows 60..64 ========
    const int y0 = 60;
    const size_t rowbase = ((size_t)(m*4 + cb) * 96 + y0) * 96;
    for (int k = tid; k < 36*48; k += 256) {
      const int rho = k / 48, px = k - (k/48)*48;
      cp16(&satT[(rowbase + (size_t)rho*96 + x0 + px)*8], &patch[(size_t)k*8]);
    }
    asm volatile("s_waitcnt vmcnt(0)" ::: "memory");
    __syncthreads();

    floatx4 acc[5];
    #pragma unroll
    for (int r = 0; r < 5; ++r) acc[r] = (floatx4){0.f, 0.f, 0.f, 0.f};

    #pragma unroll
    for (int jbi = 0; jbi < 2; ++jbi) {
      const int jb = wave*2 + jbi;
      const int apx = pr + jb*4 + q;
      const u16* bp = gP + ((size_t)cb*1024 + (size_t)(jb*4+q))*128 + (size_t)pr*8;

      uint4 Br[8];
      #pragma unroll
      for (int ii = 0; ii < 8; ++ii) Br[ii] = *(const uint4*)(bp + (size_t)ii*4096);
      uint4 Ah[8];
      #pragma unroll
      for (int s = 0; s < 6; ++s) Ah[s] = *(const uint4*)(&patch[((size_t)s*48 + apx)*8]);

      #pragma unroll
      for (int i = 0; i < 32; ++i) {
        if (i < 30)
          Ah[(i+6)&7] = *(const uint4*)(&patch[((size_t)(i+6)*48 + apx)*8]);
        const bf16x8 bf = __builtin_bit_cast(bf16x8, Br[i&7]);
        if (i < 24)
          Br[(i+8)&7] = *(const uint4*)(bp + (size_t)(i+8)*4096);
        __builtin_amdgcn_s_setprio(1);
        #pragma unroll
        for (int r = 0; r < 5; ++r)
          acc[r] = __builtin_amdgcn_mfma_f32_16x16x32_bf16(
              __builtin_bit_cast(bf16x8, Ah[(i+r)&7]), bf, acc[r], 0, 0, 0);
        __builtin_amdgcn_s_setprio(0);
      }
    }

    __syncthreads();
    float* red = (float*)patch;
    #pragma unroll
    for (int u = 0; u < 20; ++u)
      red[((size_t)wave*64 + lane)*21 + u] = acc[u>>2][u&3];
    __syncthreads();
    if (pr < 8) {
      const int fw = wave;
      #pragma unroll
      for (int r = 0; r < 5; ++r) {
        float s = 0.f;
        #pragma unroll
        for (int w = 0; w < 4; ++w)
          s += red[((size_t)w*64 + lane)*21 + r*4 + fw]
             + red[((size_t)w*64 + (lane^8))*21 + r*4 + fw];
        const int x = x0 + q*4 + fw;
        corr_p[(size_t)cb*270400 + ((size_t)(m*8+pr)*65 + (y0+r))*65 + x] = s;
      }
    }
  }
}

// ---- K3: streaming normalize/max + candidate collect + gmax gather. ----
__global__ __launch_bounds__(256) void k_post(
    const float* __restrict__ corr_p, const float* __restrict__ part,
    const float* __restrict__ nrmp, const float* __restrict__ gnrm,
    const int* __restrict__ tm,
    u32* __restrict__ pmaxE, u32* __restrict__ grpcnt,
    u32* __restrict__ candcnt, u64* __restrict__ cand,
    float* __restrict__ cscN, float* __restrict__ pscN,
    float* __restrict__ out)
{
  __shared__ float red[8];
  __shared__ int s_last;

  const int bi = blockIdx.x;
  const int m = bi / 40, n = (bi / 5) & 7, yc = bi % 5, g = m*8 + n;
  const int t = threadIdx.x;
  const int wv = t >> 6, ln = t & 63;
  const bool diag = (m == n);

  float v0 = (t < 96) ? nrmp[m*96 + t] : 0.f;
  v0 = wred_sum(v0);
  if (ln == 0) red[wv] = v0;
  __syncthreads();
  const float snrm2 = red[0] + red[1] + red[2] + red[3];
  const float srn = 1.f / fmaxf(sqrtf(snrm2), 1e-12f);
  const float grn = 1.f / fmaxf(sqrtf(gnrm[n]), 1e-12f);
  const float cscale = grn * srn, pscale = srn * srn;
  const int method = tm[0];
  if (diag && t == 0) { cscN[n] = cscale; pscN[n] = pscale; }   // for k_refine

  const float* cp = corr_p + (size_t)g*4225;
  const float* pp = part + (size_t)m*4225;
  const int i0 = yc*845, i1 = i0 + 845;
  float vv[4];
  float bestv = -3.4e38f;
  #pragma unroll
  for (int k = 0; k < 4; ++k) {
    const int idx = i0 + k*256 + t;
    float v = -3.4e38f;
    if (idx < i1) {
      const float c = cp[idx] + cp[idx+270400] + cp[idx+540800] + cp[idx+811200];
      const float pt = pp[idx] * pscale;
      float denom = (method == 0) ? sqrtf(pt) : pt;
      denom = fmaxf(denom, 1e-12f);
      v = c * cscale / denom;
    }
    vv[k] = v;
    bestv = fmaxf(bestv, v);
  }
  __syncthreads();                    // red WAR guard
  const float bw = wred_max(bestv);
  if (ln == 0) red[wv] = bw;
  __syncthreads();
  const float bmax = fmaxf(fmaxf(red[0], red[1]), fmaxf(red[2], red[3]));
  if (t == 0) atomicExch(&pmaxE[bi], encf(bmax));

  if (diag) {
    // collect candidate superset: within 3e-3 of BLOCK max (global filter in k_refine)
    const float lthr = bmax - 3e-3f;
    #pragma unroll
    for (int k = 0; k < 4; ++k) {
      const int idx = i0 + k*256 + t;
      if (idx < i1 && vv[k] >= lthr) {
        const u32 s = atomicAdd(&candcnt[n], 1u);
        if (s < 128)
          atomicExch(&cand[n*128 + s],
                     ((u64)__builtin_bit_cast(u32, vv[k]) << 32) | (u32)idx);
      }
    }
  }
  __syncthreads();
  if (t == 0) s_last = (atomicAdd(&grpcnt[g], 1u) == 4u) ? 1 : 0;
  __syncthreads();
  if (!s_last) return;

  if (t < 5) {
    const u32 e = atomicOr(&pmaxE[g*5 + t], 0u);
    const u32 u = (e >> 31) ? (e & 0x7FFFFFFFu) : ~e;
    red[t] = __builtin_bit_cast(float, u);
  }
  __syncthreads();
  const float gmax = fmaxf(fmaxf(fmaxf(red[0], red[1]), fmaxf(red[2], red[3])), red[4]);
  if (t == 0) out[g] = gmax;
}

// ---- K4: parallel refine + mask. 1024 blocks = 8 n x 128 candidate slots.
//      Each active slot computes one exact f32 dot (coalesced, 256 threads),
//      atomicMax's a (value,~idx) key; last slot per n writes the mask.
//      NO __threadfence (R4 lesson: it is an L2 wb/inv storm, +45us). ----
__global__ __launch_bounds__(256) void k_refine(
    const float* __restrict__ part, const int* __restrict__ tm,
    const float* __restrict__ grd, const float* __restrict__ sat,
    const float* __restrict__ gmask,
    const u32* __restrict__ candcnt, const u64* __restrict__ cand,
    const float* __restrict__ cscN, const float* __restrict__ pscN,
    u32* __restrict__ rdone, u64* __restrict__ bestu,
    float* __restrict__ out)
{
  __shared__ float red[4];
  __shared__ int s_last;

  const int bid = blockIdx.x;
  const int n = bid >> 7, ci = bid & 127;
  const int t = threadIdx.x;
  const int wv = t >> 6, ln = t & 63;

  u32 nc = candcnt[n]; if (nc > 128u) nc = 128u;
  bool act = (ci < (int)nc);
  int idx = 0;
  if (act) {
    const u64 pk = cand[n*128 + ci];
    const float vf = __builtin_bit_cast(float, (u32)(pk >> 32));
    idx = (int)(u32)pk;
    act = (vf >= out[9*n] - 3e-3f);     // global filter (gmax from k_post)
  }
  if (act) {
    const int y = idx / 65, x = idx - y*65;
    const int i0 = t >> 5, j = t & 31;   // lanes sweep j: coalesced 128B runs
    const float* gb = grd + (size_t)n*32768 + i0*32 + j;
    const float* sb = sat + (((size_t)n*32*128) + 16 + y + i0)*128 + 16 + x + j;
    float a = 0.f;
    #pragma unroll 4
    for (int c = 0; c < 32; ++c) {
      #pragma unroll
      for (int ii = 0; ii < 4; ++ii)
        a += gb[(size_t)(c*32 + ii*8)*32] * sb[((size_t)c*128 + ii*8)*128];
    }
    a = wred_sum(a);
    if (ln == 0) red[wv] = a;
    __syncthreads();
    if (t == 0) {
      const float tot = red[0] + red[1] + red[2] + red[3];
      const float pt = part[(size_t)n*4225 + idx] * pscN[n];
      float denom = (tm[0] == 0) ? sqrtf(pt) : pt;
      denom = fmaxf(denom, 1e-12f);
      const float v = tot * cscN[n] / denom;
      const u64 key = ((u64)encf(v) << 32) | (u64)(0xFFFFFFFFu - (u32)idx);
      atomicMax(&bestu[n], key);
    }
  }
  __syncthreads();     // drains vmcnt(0): bestu atomicMax committed before rdone
  if (t == 0) s_last = (atomicAdd(&rdone[n], 1u) == 127u) ? 1 : 0;
  __syncthreads();
  if (!s_last) return;

  const u64 bk = atomicAdd(&bestu[n], 0ULL);
  const int bix = (int)(0xFFFFFFFFu - (u32)bk);
  const int ph = bix / 65, pw = bix - (bix/65)*65;
  for (int p = t; p < 9216; p += 256) {
    const int yy = p / 96, xx = p - yy*96;
    float val = 0.f;
    if (yy >= ph && yy < ph+32 && xx >= pw && xx < pw+32)
      val = gmask[n*1024 + (yy-ph)*32 + (xx-pw)];
    out[64 + (size_t)n*9216 + p] = val;
  }
}

extern "C" void kernel_launch(void* const* d_in, const int* in_sizes, int n_in,
                              void* d_out, int out_size, void* d_ws, size_t ws_size,
                              hipStream_t stream) {
  const float* grd = (const float*)d_in[0];
  const float* sat = (const float*)d_in[1];
  const int*   tm  = (const int*)d_in[2];
  float* out = (float*)d_out;
  char* ws = (char*)d_ws;

  float* corrp = (float*)(ws + OFF_CORRP);
  u16*   sTh   = (u16*)(ws + OFF_SATT);
  u16*   gP    = (u16*)(ws + OFF_GRDP);
  float* s2    = (float*)(ws + OFF_S2);
  float* part  = (float*)(ws + OFF_PART);
  float* nrmp  = (float*)(ws + OFF_NRMP);
  float* gnrm  = (float*)(ws + OFF_GNRM);
  float* gmask = (float*)(ws + OFF_MASK);
  u32*   pmaxE = (u32*)(ws + OFF_PMAX);
  u32*   cnts  = (u32*)(ws + OFF_CNT);
  u32*   candcnt = cnts + 64;
  u32*   rdone = cnts + 88;
  u64*   bestu = (u64*)(ws + OFF_CNT + 384);
  float* cscN  = (float*)(cnts + 112);
  float* pscN  = (float*)(cnts + 120);
  u64*   cand  = (u64*)(ws + OFF_CAND);

  k_prep<<<777,  256, 0, stream>>>(grd, sat, sTh, gP, s2, nrmp, gnrm, gmask, cnts);
  k_conv<<<1128, 256, 0, stream>>>(sTh, gP, s2, corrp, part);
  k_post<<<320,  256, 0, stream>>>(corrp, part, nrmp, gnrm, tm,
                                   pmaxE, cnts, candcnt, cand, cscN, pscN, out);
  k_refine<<<1024, 256, 0, stream>>>(part, tm, grd, sat, gmask,
                                     candcnt, cand, cscN, pscN,
                                     rdone, bestu, out);
}